// Round 5
// baseline (493.184 us; speedup 1.0000x reference)
//
#include <hip/hip_runtime.h>
#include <math.h>

// N=50000 nodes, E=800000 edges, F_IN=33, H=128, G=64 graphs.
static constexpr int F_IN = 33;
static constexpr int H    = 128;
static constexpr int GG   = 64;

typedef __attribute__((ext_vector_type(8))) short short8;
typedef __attribute__((ext_vector_type(4))) float f32x4;

__device__ __forceinline__ unsigned short f2bf(float f) {
  union { float f; unsigned u; } v; v.f = f;
  unsigned r = v.u + 0x7fffu + ((v.u >> 16) & 1u);   // RNE
  return (unsigned short)(r >> 16);
}
__device__ __forceinline__ float bf2f(unsigned short b) {
  union { unsigned u; float f; } v; v.u = ((unsigned)b) << 16;
  return v.f;
}

// Async global->LDS copy, 16B per lane, wave-uniform LDS base (lane-linear).
using gas_u32 = const __attribute__((address_space(1))) unsigned int*;
using las_u32 = __attribute__((address_space(3))) unsigned int*;
__device__ __forceinline__ void ld_lds16(const unsigned short* g, unsigned short* l) {
  __builtin_amdgcn_global_load_lds((gas_u32)(const void*)g, (las_u32)(void*)l, 16, 0, 0);
}

// ---------------- CSR build ----------------

__global__ void hist_kernel(const int* __restrict__ dst, int* __restrict__ cnt, int E) {
  int i = blockIdx.x * 256 + threadIdx.x;
  if (i < E) atomicAdd(&cnt[dst[i]], 1);
}

__global__ void block_reduce(const int* __restrict__ cnt, int* __restrict__ partial, int n) {
  __shared__ int s[256];
  const int t = threadIdx.x;
  const int base = blockIdx.x * 1024;
  int sum = 0;
  for (int i = t; i < 1024; i += 256) {
    int idx = base + i;
    if (idx < n) sum += cnt[idx];
  }
  s[t] = sum;
  __syncthreads();
  for (int off = 128; off > 0; off >>= 1) {
    if (t < off) s[t] += s[t + off];
    __syncthreads();
  }
  if (t == 0) partial[blockIdx.x] = s[0];
}

__global__ void scan_partials(int* __restrict__ partial, int nb, int* __restrict__ total_out) {
  __shared__ int s[256];
  const int t = threadIdx.x;
  int carry = 0;
  for (int base = 0; base < nb; base += 256) {
    int v = (base + t < nb) ? partial[base + t] : 0;
    s[t] = v;
    __syncthreads();
    for (int off = 1; off < 256; off <<= 1) {
      int add = (t >= off) ? s[t - off] : 0;
      __syncthreads();
      s[t] += add;
      __syncthreads();
    }
    if (base + t < nb) partial[base + t] = s[t] - v + carry;
    carry += s[255];
    __syncthreads();
  }
  if (t == 0) *total_out = carry;
}

__global__ void block_scan(int* __restrict__ cnt_cursor, const int* __restrict__ partial,
                           int* __restrict__ rowptr, int n) {
  __shared__ int s[256];
  const int t = threadIdx.x;
  const int base = blockIdx.x * 1024;
  int v[4];
  int sum = 0;
#pragma unroll
  for (int j = 0; j < 4; ++j) {
    int idx = base + t * 4 + j;
    v[j] = (idx < n) ? cnt_cursor[idx] : 0;
    sum += v[j];
  }
  s[t] = sum;
  __syncthreads();
  for (int off = 1; off < 256; off <<= 1) {
    int add = (t >= off) ? s[t - off] : 0;
    __syncthreads();
    s[t] += add;
    __syncthreads();
  }
  int excl = s[t] - sum + partial[blockIdx.x];
#pragma unroll
  for (int j = 0; j < 4; ++j) {
    int idx = base + t * 4 + j;
    if (idx < n) {
      rowptr[idx] = excl;
      cnt_cursor[idx] = excl;
    }
    excl += v[j];
  }
}

__global__ void build_kernel(const int* __restrict__ src, const int* __restrict__ dst,
                             int* __restrict__ cursor, int* __restrict__ srcList, int E) {
  int i = blockIdx.x * 256 + threadIdx.x;
  if (i < E) {
    int pos = atomicAdd(&cursor[dst[i]], 1);
    srcList[pos] = src[i];
  }
}

// ------- W transpose+convert to bf16, XOR-swizzled 16B chunks per row -------
// o[n][ (chunk^ (n&7))*8 + k%8 ] = W[k][n]; chunk = k/8. K zero-padded to Kp.

struct WConvArgs {
  const float* w[6];
  unsigned short* o[6];
  int K[6], Kp[6];
};

__global__ void wconv(WConvArgs a) {
  const int wi = blockIdx.y;
  const int i = blockIdx.x * 256 + threadIdx.x;
  const int Kp = a.Kp[wi];
  if (i >= H * Kp) return;
  const int nn = i / Kp, k = i - nn * Kp;
  float v = (k < a.K[wi]) ? a.w[wi][(size_t)k * H + nn] : 0.f;
  a.o[wi][(size_t)nn * Kp + (((k >> 3) ^ (nn & 7)) << 3) + (k & 7)] = f2bf(v);
}

// ---------------- Aggregation (gather), bf16 h, swizzled rows ---------------
// Row r = 256B = 32 uint2; logical dword d lives at ((d>>2)^(r&7))*4 + (d&3).
// Two edges per vmem instruction: lanes 0-31 -> edge i, lanes 32-63 -> edge
// i+1, each lane one uint2 (4 bf16 features). Final cross-half combine via
// __shfl_down(.,32); lanes 0-31 add self and store.

__global__ void gather_h(const unsigned short* __restrict__ h, const int* __restrict__ rowptr,
                         const int* __restrict__ srcList, unsigned short* __restrict__ out, int n) {
  const int node = blockIdx.x;
  const int lane = threadIdx.x;           // 64
  const int half = lane >> 5;             // which edge of the pair
  const int l32 = lane & 31;
  const uint2* h4 = (const uint2*)h;      // row = 32 uint2
  const int c4 = l32 >> 1, p1 = l32 & 1;  // 16B chunk, uint2 parity in chunk
  auto rowoff = [&](int r) { return (size_t)r * 32 + (((c4 ^ (r & 7)) << 1) | p1); };

  const int beg = rowptr[node], end = rowptr[node + 1];
  float a0 = 0.f, a1 = 0.f, a2 = 0.f, a3 = 0.f;
  int i = beg;
  for (; i + 7 < end; i += 8) {
    int s0 = srcList[i + half];
    int s1 = srcList[i + 2 + half];
    int s2 = srcList[i + 4 + half];
    int s3 = srcList[i + 6 + half];
    uint2 v0 = h4[rowoff(s0)];
    uint2 v1 = h4[rowoff(s1)];
    uint2 v2 = h4[rowoff(s2)];
    uint2 v3 = h4[rowoff(s3)];
    a0 += (bf2f((unsigned short)v0.x) + bf2f((unsigned short)v1.x)) +
          (bf2f((unsigned short)v2.x) + bf2f((unsigned short)v3.x));
    a1 += (bf2f((unsigned short)(v0.x >> 16)) + bf2f((unsigned short)(v1.x >> 16))) +
          (bf2f((unsigned short)(v2.x >> 16)) + bf2f((unsigned short)(v3.x >> 16)));
    a2 += (bf2f((unsigned short)v0.y) + bf2f((unsigned short)v1.y)) +
          (bf2f((unsigned short)v2.y) + bf2f((unsigned short)v3.y));
    a3 += (bf2f((unsigned short)(v0.y >> 16)) + bf2f((unsigned short)(v1.y >> 16))) +
          (bf2f((unsigned short)(v2.y >> 16)) + bf2f((unsigned short)(v3.y >> 16)));
  }
  for (; i + 1 < end; i += 2) {
    int s0 = srcList[i + half];
    uint2 v = h4[rowoff(s0)];
    a0 += bf2f((unsigned short)v.x);
    a1 += bf2f((unsigned short)(v.x >> 16));
    a2 += bf2f((unsigned short)v.y);
    a3 += bf2f((unsigned short)(v.y >> 16));
  }
  if (i < end && half == 0) {             // odd tail, half 0 only
    int s0 = srcList[i];
    uint2 v = h4[rowoff(s0)];
    a0 += bf2f((unsigned short)v.x);
    a1 += bf2f((unsigned short)(v.x >> 16));
    a2 += bf2f((unsigned short)v.y);
    a3 += bf2f((unsigned short)(v.y >> 16));
  }
  // combine halves (lane gets lane+32's accumulators)
  float b0 = __shfl_down(a0, 32), b1 = __shfl_down(a1, 32);
  float b2 = __shfl_down(a2, 32), b3 = __shfl_down(a3, 32);
  if (half == 0) {
    uint2 sv = h4[rowoff(node)];
    a0 += b0 + bf2f((unsigned short)sv.x);
    a1 += b1 + bf2f((unsigned short)(sv.x >> 16));
    a2 += b2 + bf2f((unsigned short)sv.y);
    a3 += b3 + bf2f((unsigned short)(sv.y >> 16));
    uint2 o;
    o.x = ((unsigned)f2bf(a1) << 16) | (unsigned)f2bf(a0);
    o.y = ((unsigned)f2bf(a3) << 16) | (unsigned)f2bf(a2);
    ((uint2*)out)[rowoff(node)] = o;
  }
}

// Layer-1 gather: fp32 x (N x 33) -> bf16 A (N x 64 ushorts, swizzled rows).
__global__ void gather_x(const float* __restrict__ x, const int* __restrict__ rowptr,
                         const int* __restrict__ srcList, unsigned short* __restrict__ out, int n) {
  const int node = blockIdx.x;
  const int lane = threadIdx.x;           // 64
  const int beg = rowptr[node], end = rowptr[node + 1];
  float acc = 0.f;
  if (lane < F_IN) acc = x[(size_t)node * F_IN + lane];
  int i = beg;
  for (; i + 3 < end; i += 4) {
    int s0 = srcList[i], s1 = srcList[i + 1], s2 = srcList[i + 2], s3 = srcList[i + 3];
    if (lane < F_IN) {
      float v0 = x[(size_t)s0 * F_IN + lane];
      float v1 = x[(size_t)s1 * F_IN + lane];
      float v2 = x[(size_t)s2 * F_IN + lane];
      float v3 = x[(size_t)s3 * F_IN + lane];
      acc += (v0 + v1) + (v2 + v3);
    }
  }
  for (; i < end; ++i) {
    if (lane < F_IN) acc += x[(size_t)srcList[i] * F_IN + lane];
  }
  out[(size_t)node * 64 + (((lane >> 3) ^ (node & 7)) << 3) + (lane & 7)] = f2bf(acc);
}

// -------- Fused GIN MLP: C = relu(relu(BN(A@W1)) @ W2 + b2), + pool ---------
// Persistent blocks (grid=256, 1 block/CU): W1,W2 staged to LDS ONCE (async),
// STATIC tile striding (block b -> tiles b, b+grid, ...; uniform cost, no
// atomic ticket). Z stays in LDS. 512 thr = 8 waves: wave w -> rows
// (w>>1)*16.., cols (w&1)*64.. (4 MFMA col-tiles).

template <int K1, bool STORE>
__global__ __launch_bounds__(512, 1) void gin_mlp(
    const unsigned short* __restrict__ Ag,   // n x K1 bf16 (swizzled rows)
    const unsigned short* __restrict__ W1t,  // 128 x K1 bf16 (swizzled)
    const unsigned short* __restrict__ W2t,  // 128 x 128 bf16 (swizzled)
    const float* __restrict__ b1, const float* __restrict__ gam,
    const float* __restrict__ bet, const float* __restrict__ mu,
    const float* __restrict__ var, const float* __restrict__ b2,
    unsigned short* __restrict__ Pout,       // n x 128 bf16 (swizzled) or null
    const int* __restrict__ batch, float* __restrict__ pool, int n) {
  __shared__ __align__(16) unsigned short W1ls[128 * K1];
  __shared__ __align__(16) unsigned short W2ls[128 * 128];
  __shared__ __align__(16) unsigned short Als[64 * K1];
  __shared__ __align__(16) unsigned short Zls[64 * 128];
  __shared__ float sc1[128], sh1[128], b2l[128];

  const int tx = threadIdx.x;
  const int wv = tx >> 6;                 // wave 0..7
  const int lane = tx & 63;
  const int q = lane >> 4, m = lane & 15;
  const int rowGroup = (wv >> 1) * 16;    // 0,16,32,48
  const int colHalf = (wv & 1) * 64;
  const int ntiles = (n + 63) >> 6;
  const int step = gridDim.x;

  // Stage W once (async; each wave copies distinct 1024B segments).
  constexpr int W1SEG = 128 * K1 / 512;
  for (int s = wv; s < W1SEG; s += 8)
    ld_lds16(W1t + s * 512 + lane * 8, &W1ls[s * 512]);
  for (int s = wv; s < 32; s += 8)
    ld_lds16(W2t + s * 512 + lane * 8, &W2ls[s * 512]);

  if (tx < 128) {                          // fold bias1 into BN affine
    float s = gam[tx] * rsqrtf(var[tx] + 1e-5f);
    sc1[tx] = s;
    sh1[tx] = bet[tx] + (b1[tx] - mu[tx]) * s;
  } else if (tx < 256) {
    b2l[tx - 128] = b2[tx - 128];
  }

  int tile = blockIdx.x;
  constexpr int ASEG = 64 * K1 / 512;
  if (tile < ntiles) {
    const unsigned short* src = Ag + (size_t)tile * 64 * K1;
    for (int s = wv; s < ASEG; s += 8)
      ld_lds16(src + s * 512 + lane * 8, &Als[s * 512]);
  }
  __syncthreads();                         // drains W + A(tile)

  while (tile < ntiles) {
    // ---- GEMM1: Z = relu(BN(A @ W1 + b1)) ----
    f32x4 acc[4];
#pragma unroll
    for (int t4 = 0; t4 < 4; ++t4) acc[t4] = (f32x4)(0.f);
    const int am = rowGroup + m;
#pragma unroll
    for (int kc = 0; kc < K1 / 32; ++kc) {
      short8 af = *(const short8*)&Als[am * K1 + (((kc * 4 + q) ^ (am & 7)) << 3)];
#pragma unroll
      for (int t4 = 0; t4 < 4; ++t4) {
        const int bn = colHalf + t4 * 16 + m;
        short8 bf = *(const short8*)&W1ls[bn * K1 + (((kc * 4 + q) ^ (bn & 7)) << 3)];
        acc[t4] = __builtin_amdgcn_mfma_f32_16x16x32_bf16(af, bf, acc[t4], 0, 0, 0);
      }
    }
#pragma unroll
    for (int t4 = 0; t4 < 4; ++t4) {       // epilogue -> Zls (bf16, swizzled)
      const int col = colHalf + t4 * 16 + m;
      const float s = sc1[col], hh = sh1[col];
#pragma unroll
      for (int reg = 0; reg < 4; ++reg) {
        const int r = rowGroup + q * 4 + reg;
        float z = fmaf(acc[t4][reg], s, hh);
        z = z > 0.f ? z : 0.f;
        Zls[r * 128 + (((col >> 3) ^ (r & 7)) << 3) + (col & 7)] = f2bf(z);
      }
    }
    __syncthreads();                       // Zls ready; Als free
    const int nt = tile + step;
    if (nt < ntiles) {                     // prefetch next A, overlaps GEMM2
      const unsigned short* src = Ag + (size_t)nt * 64 * K1;
      for (int s = wv; s < ASEG; s += 8)
        ld_lds16(src + s * 512 + lane * 8, &Als[s * 512]);
    }
    // ---- GEMM2: C = relu(Z @ W2 + b2) ----
#pragma unroll
    for (int t4 = 0; t4 < 4; ++t4) acc[t4] = (f32x4)(0.f);
#pragma unroll
    for (int kc = 0; kc < 4; ++kc) {
      short8 af = *(const short8*)&Zls[am * 128 + (((kc * 4 + q) ^ (am & 7)) << 3)];
#pragma unroll
      for (int t4 = 0; t4 < 4; ++t4) {
        const int bn = colHalf + t4 * 16 + m;
        short8 bf = *(const short8*)&W2ls[bn * 128 + (((kc * 4 + q) ^ (bn & 7)) << 3)];
        acc[t4] = __builtin_amdgcn_mfma_f32_16x16x32_bf16(af, bf, acc[t4], 0, 0, 0);
      }
    }
    const int r0 = tile * 64 + rowGroup + q * 4;
    int gb4[4];
#pragma unroll
    for (int reg = 0; reg < 4; ++reg) gb4[reg] = (r0 + reg < n) ? batch[r0 + reg] : -1;
#pragma unroll
    for (int t4 = 0; t4 < 4; ++t4) {
      const int col = colHalf + t4 * 16 + m;
      float v[4];
#pragma unroll
      for (int reg = 0; reg < 4; ++reg) {
        float z = acc[t4][reg] + b2l[col];
        v[reg] = z > 0.f ? z : 0.f;
      }
      if constexpr (STORE) {
#pragma unroll
        for (int reg = 0; reg < 4; ++reg) {
          const int row = r0 + reg;
          if (row < n)
            Pout[(size_t)row * 128 + (((col >> 3) ^ (row & 7)) << 3) + (col & 7)] = f2bf(v[reg]);
        }
      }
      int gcur = -1; float ps = 0.f;       // batch sorted -> run-length flush
#pragma unroll
      for (int reg = 0; reg < 4; ++reg) {
        if (gb4[reg] < 0) break;
        if (gb4[reg] != gcur) {
          if (gcur >= 0) atomicAdd(pool + gcur * H + col, ps);
          gcur = gb4[reg]; ps = v[reg];
        } else {
          ps += v[reg];
        }
      }
      if (gcur >= 0) atomicAdd(pool + gcur * H + col, ps);
    }
    __syncthreads();                       // drains prefetch; Zls free
    tile = nt;
  }
}

// ---------------- Head MLP: [G,384] -> 50 -> 20 -> 1 -> sigmoid -------------

__global__ void head_kernel(const float* __restrict__ pools,
                            const float* __restrict__ l1w, const float* __restrict__ l1b,
                            const float* __restrict__ l2w, const float* __restrict__ l2b,
                            const float* __restrict__ l3w, const float* __restrict__ l3b,
                            float* __restrict__ out) {
  const int g = blockIdx.x;
  const int t = threadIdx.x;  // 64 threads
  __shared__ float hin[3 * H];
  __shared__ float t1[50];
  __shared__ float t2[20];
  for (int idx = t; idx < 3 * H; idx += 64) {
    int l = idx >> 7, f = idx & 127;
    hin[idx] = pools[(size_t)l * GG * H + (size_t)g * H + f];
  }
  __syncthreads();
  if (t < 50) {
    float s = l1b[t];
    for (int k = 0; k < 3 * H; ++k) s = fmaf(hin[k], l1w[k * 50 + t], s);
    t1[t] = s > 0.f ? s : 0.f;
  }
  __syncthreads();
  if (t < 20) {
    float s = l2b[t];
    for (int k = 0; k < 50; ++k) s = fmaf(t1[k], l2w[k * 20 + t], s);
    t2[t] = s > 0.f ? s : 0.f;
  }
  __syncthreads();
  if (t == 0) {
    float s = l3b[0];
    for (int k = 0; k < 20; ++k) s = fmaf(t2[k], l3w[k], s);
    out[g] = 1.f / (1.f + expf(-s));
  }
}

// ---------------- launch ----------------------------------------------------

extern "C" void kernel_launch(void* const* d_in, const int* in_sizes, int n_in,
                              void* d_out, int out_size, void* d_ws, size_t ws_size,
                              hipStream_t stream) {
  const float* x    = (const float*)d_in[0];
  const int* ei     = (const int*)d_in[1];
  const int* batch  = (const int*)d_in[2];
  const int N = in_sizes[2];
  const int E = in_sizes[1] / 2;
  const int* src = ei;
  const int* dst = ei + E;

  const float* w1[3]; const float* b1[3]; const float* gm[3]; const float* be[3];
  const float* mu[3]; const float* vr[3]; const float* w2[3]; const float* b2[3];
  for (int l = 0; l < 3; ++l) {
    int b = 3 + 8 * l;
    w1[l] = (const float*)d_in[b + 0];
    b1[l] = (const float*)d_in[b + 1];
    gm[l] = (const float*)d_in[b + 2];
    be[l] = (const float*)d_in[b + 3];
    mu[l] = (const float*)d_in[b + 4];
    vr[l] = (const float*)d_in[b + 5];
    w2[l] = (const float*)d_in[b + 6];
    b2[l] = (const float*)d_in[b + 7];
  }
  const float* l1w = (const float*)d_in[27];
  const float* l1b = (const float*)d_in[28];
  const float* l2w = (const float*)d_in[29];
  const float* l2b = (const float*)d_in[30];
  const float* l3w = (const float*)d_in[31];
  const float* l3b = (const float*)d_in[32];

  // workspace carve-up
  char* ws = (char*)d_ws;
  size_t off = 0;
  auto take = [&](size_t bytes) {
    size_t p = off;
    off += (bytes + 255) & ~(size_t)255;
    return p;
  };
  unsigned short* A = (unsigned short*)(ws + take((size_t)N * H * 2));  // agg (bf16, swizzled)
  unsigned short* P = (unsigned short*)(ws + take((size_t)N * H * 2));  // layer out (bf16, swizzled)
  float* pools  = (float*)(ws + take((size_t)3 * GG * H * 4));
  int* rowptr   = (int*)(ws + take((size_t)(N + 1) * 4));
  int* cursor   = (int*)(ws + take((size_t)N * 4));
  int* srcList  = (int*)(ws + take((size_t)E * 4));
  int* partial  = (int*)(ws + take((size_t)1024 * 4));
  unsigned short* Wt[6];
  for (int i = 0; i < 6; ++i) Wt[i] = (unsigned short*)(ws + take((size_t)H * H * 2));
  (void)ws_size; (void)n_in; (void)out_size;

  const int eb = (E + 255) / 256;
  const int nb = (N + 1023) / 1024;

  hipMemsetAsync(cursor, 0, (size_t)N * 4, stream);
  hipMemsetAsync(pools, 0, (size_t)3 * GG * H * 4, stream);

  // W transpose+convert+swizzle (all 6 in one launch)
  WConvArgs wa;
  wa.w[0] = w1[0]; wa.K[0] = F_IN; wa.Kp[0] = 64;
  wa.w[1] = w2[0]; wa.K[1] = H;    wa.Kp[1] = H;
  wa.w[2] = w1[1]; wa.K[2] = H;    wa.Kp[2] = H;
  wa.w[3] = w2[1]; wa.K[3] = H;    wa.Kp[3] = H;
  wa.w[4] = w1[2]; wa.K[4] = H;    wa.Kp[4] = H;
  wa.w[5] = w2[2]; wa.K[5] = H;    wa.Kp[5] = H;
  for (int i = 0; i < 6; ++i) wa.o[i] = Wt[i];
  wconv<<<dim3((H * H + 255) / 256, 6), 256, 0, stream>>>(wa);

  // CSR by dst
  hist_kernel<<<eb, 256, 0, stream>>>(dst, cursor, E);
  block_reduce<<<nb, 256, 0, stream>>>(cursor, partial, N);
  scan_partials<<<1, 256, 0, stream>>>(partial, nb, rowptr + N);
  block_scan<<<nb, 256, 0, stream>>>(cursor, partial, rowptr, N);
  build_kernel<<<eb, 256, 0, stream>>>(src, dst, cursor, srcList, E);

  // ---- layer 1 (K padded 33 -> 64) ----
  gather_x<<<N, 64, 0, stream>>>(x, rowptr, srcList, A, N);
  gin_mlp<64, true><<<256, 512, 0, stream>>>(
      A, Wt[0], Wt[1], b1[0], gm[0], be[0], mu[0], vr[0], b2[0],
      P, batch, pools, N);

  // ---- layer 2 ----
  gather_h<<<N, 64, 0, stream>>>(P, rowptr, srcList, A, N);
  gin_mlp<128, true><<<256, 512, 0, stream>>>(
      A, Wt[2], Wt[3], b1[1], gm[1], be[1], mu[1], vr[1], b2[1],
      P, batch, pools + GG * H, N);

  // ---- layer 3 (h3 pooled only) ----
  gather_h<<<N, 64, 0, stream>>>(P, rowptr, srcList, A, N);
  gin_mlp<128, false><<<256, 512, 0, stream>>>(
      A, Wt[4], Wt[5], b1[2], gm[2], be[2], mu[2], vr[2], b2[2],
      nullptr, batch, pools + 2 * GG * H, N);

  // ---- head ----
  head_kernel<<<GG, 64, 0, stream>>>(pools, l1w, l1b, l2w, l2b, l3w, l3b, (float*)d_out);
}

// Round 6
// 400.714 us; speedup vs baseline: 1.2308x; 1.2308x over previous
//
#include <hip/hip_runtime.h>
#include <math.h>

// N=50000 nodes, E=800000 edges, F_IN=33, H=128, G=64 graphs.
static constexpr int F_IN = 33;
static constexpr int H    = 128;
static constexpr int GG   = 64;

typedef __attribute__((ext_vector_type(8))) short short8;
typedef __attribute__((ext_vector_type(4))) float f32x4;

__device__ __forceinline__ unsigned short f2bf(float f) {
  union { float f; unsigned u; } v; v.f = f;
  unsigned r = v.u + 0x7fffu + ((v.u >> 16) & 1u);   // RNE
  return (unsigned short)(r >> 16);
}
__device__ __forceinline__ float bf2f(unsigned short b) {
  union { unsigned u; float f; } v; v.u = ((unsigned)b) << 16;
  return v.f;
}

// Async global->LDS copy, 16B per lane, wave-uniform LDS base (lane-linear).
using gas_u32 = const __attribute__((address_space(1))) unsigned int*;
using las_u32 = __attribute__((address_space(3))) unsigned int*;
__device__ __forceinline__ void ld_lds16(const unsigned short* g, unsigned short* l) {
  __builtin_amdgcn_global_load_lds((gas_u32)(const void*)g, (las_u32)(void*)l, 16, 0, 0);
}

// ---------------- CSR build ----------------

__global__ void hist_kernel(const int* __restrict__ dst, int* __restrict__ cnt, int E) {
  int i = blockIdx.x * 256 + threadIdx.x;
  if (i < E) atomicAdd(&cnt[dst[i]], 1);
}

__global__ void block_reduce(const int* __restrict__ cnt, int* __restrict__ partial, int n) {
  __shared__ int s[256];
  const int t = threadIdx.x;
  const int base = blockIdx.x * 1024;
  int sum = 0;
  for (int i = t; i < 1024; i += 256) {
    int idx = base + i;
    if (idx < n) sum += cnt[idx];
  }
  s[t] = sum;
  __syncthreads();
  for (int off = 128; off > 0; off >>= 1) {
    if (t < off) s[t] += s[t + off];
    __syncthreads();
  }
  if (t == 0) partial[blockIdx.x] = s[0];
}

__global__ void scan_partials(int* __restrict__ partial, int nb, int* __restrict__ total_out) {
  __shared__ int s[256];
  const int t = threadIdx.x;
  int carry = 0;
  for (int base = 0; base < nb; base += 256) {
    int v = (base + t < nb) ? partial[base + t] : 0;
    s[t] = v;
    __syncthreads();
    for (int off = 1; off < 256; off <<= 1) {
      int add = (t >= off) ? s[t - off] : 0;
      __syncthreads();
      s[t] += add;
      __syncthreads();
    }
    if (base + t < nb) partial[base + t] = s[t] - v + carry;
    carry += s[255];
    __syncthreads();
  }
  if (t == 0) *total_out = carry;
}

__global__ void block_scan(int* __restrict__ cnt_cursor, const int* __restrict__ partial,
                           int* __restrict__ rowptr, int n) {
  __shared__ int s[256];
  const int t = threadIdx.x;
  const int base = blockIdx.x * 1024;
  int v[4];
  int sum = 0;
#pragma unroll
  for (int j = 0; j < 4; ++j) {
    int idx = base + t * 4 + j;
    v[j] = (idx < n) ? cnt_cursor[idx] : 0;
    sum += v[j];
  }
  s[t] = sum;
  __syncthreads();
  for (int off = 1; off < 256; off <<= 1) {
    int add = (t >= off) ? s[t - off] : 0;
    __syncthreads();
    s[t] += add;
    __syncthreads();
  }
  int excl = s[t] - sum + partial[blockIdx.x];
#pragma unroll
  for (int j = 0; j < 4; ++j) {
    int idx = base + t * 4 + j;
    if (idx < n) {
      rowptr[idx] = excl;
      cnt_cursor[idx] = excl;
    }
    excl += v[j];
  }
}

__global__ void build_kernel(const int* __restrict__ src, const int* __restrict__ dst,
                             int* __restrict__ cursor, int* __restrict__ srcList, int E) {
  int i = blockIdx.x * 256 + threadIdx.x;
  if (i < E) {
    int pos = atomicAdd(&cursor[dst[i]], 1);
    srcList[pos] = src[i];
  }
}

// ------- W transpose+convert to bf16, XOR-swizzled 16B chunks per row -------
// o[n][ (chunk^ (n&7))*8 + k%8 ] = W[k][n]; chunk = k/8. K zero-padded to Kp.

struct WConvArgs {
  const float* w[6];
  unsigned short* o[6];
  int K[6], Kp[6];
};

__global__ void wconv(WConvArgs a) {
  const int wi = blockIdx.y;
  const int i = blockIdx.x * 256 + threadIdx.x;
  const int Kp = a.Kp[wi];
  if (i >= H * Kp) return;
  const int nn = i / Kp, k = i - nn * Kp;
  float v = (k < a.K[wi]) ? a.w[wi][(size_t)k * H + nn] : 0.f;
  a.o[wi][(size_t)nn * Kp + (((k >> 3) ^ (nn & 7)) << 3) + (k & 7)] = f2bf(v);
}

// ---------------- Aggregation (gather), bf16 h, swizzled rows ---------------
// Row r = 256B = 32 uint2; logical dword d lives at ((d>>2)^(r&7))*4 + (d&3).
// Two edges per vmem instruction: lanes 0-31 -> edge i, lanes 32-63 -> edge
// i+1, each lane one uint2 (4 bf16 features). Final cross-half combine via
// __shfl_down(.,32); lanes 0-31 add self and store.

__global__ void gather_h(const unsigned short* __restrict__ h, const int* __restrict__ rowptr,
                         const int* __restrict__ srcList, unsigned short* __restrict__ out, int n) {
  const int node = blockIdx.x;
  const int lane = threadIdx.x;           // 64
  const int half = lane >> 5;             // which edge of the pair
  const int l32 = lane & 31;
  const uint2* h4 = (const uint2*)h;      // row = 32 uint2
  const int c4 = l32 >> 1, p1 = l32 & 1;  // 16B chunk, uint2 parity in chunk
  auto rowoff = [&](int r) { return (size_t)r * 32 + (((c4 ^ (r & 7)) << 1) | p1); };

  const int beg = rowptr[node], end = rowptr[node + 1];
  float a0 = 0.f, a1 = 0.f, a2 = 0.f, a3 = 0.f;
  int i = beg;
  for (; i + 7 < end; i += 8) {
    int s0 = srcList[i + half];
    int s1 = srcList[i + 2 + half];
    int s2 = srcList[i + 4 + half];
    int s3 = srcList[i + 6 + half];
    uint2 v0 = h4[rowoff(s0)];
    uint2 v1 = h4[rowoff(s1)];
    uint2 v2 = h4[rowoff(s2)];
    uint2 v3 = h4[rowoff(s3)];
    a0 += (bf2f((unsigned short)v0.x) + bf2f((unsigned short)v1.x)) +
          (bf2f((unsigned short)v2.x) + bf2f((unsigned short)v3.x));
    a1 += (bf2f((unsigned short)(v0.x >> 16)) + bf2f((unsigned short)(v1.x >> 16))) +
          (bf2f((unsigned short)(v2.x >> 16)) + bf2f((unsigned short)(v3.x >> 16)));
    a2 += (bf2f((unsigned short)v0.y) + bf2f((unsigned short)v1.y)) +
          (bf2f((unsigned short)v2.y) + bf2f((unsigned short)v3.y));
    a3 += (bf2f((unsigned short)(v0.y >> 16)) + bf2f((unsigned short)(v1.y >> 16))) +
          (bf2f((unsigned short)(v2.y >> 16)) + bf2f((unsigned short)(v3.y >> 16)));
  }
  for (; i + 1 < end; i += 2) {
    int s0 = srcList[i + half];
    uint2 v = h4[rowoff(s0)];
    a0 += bf2f((unsigned short)v.x);
    a1 += bf2f((unsigned short)(v.x >> 16));
    a2 += bf2f((unsigned short)v.y);
    a3 += bf2f((unsigned short)(v.y >> 16));
  }
  if (i < end && half == 0) {             // odd tail, half 0 only
    int s0 = srcList[i];
    uint2 v = h4[rowoff(s0)];
    a0 += bf2f((unsigned short)v.x);
    a1 += bf2f((unsigned short)(v.x >> 16));
    a2 += bf2f((unsigned short)v.y);
    a3 += bf2f((unsigned short)(v.y >> 16));
  }
  // combine halves (lane gets lane+32's accumulators)
  float b0 = __shfl_down(a0, 32), b1 = __shfl_down(a1, 32);
  float b2 = __shfl_down(a2, 32), b3 = __shfl_down(a3, 32);
  if (half == 0) {
    uint2 sv = h4[rowoff(node)];
    a0 += b0 + bf2f((unsigned short)sv.x);
    a1 += b1 + bf2f((unsigned short)(sv.x >> 16));
    a2 += b2 + bf2f((unsigned short)sv.y);
    a3 += b3 + bf2f((unsigned short)(sv.y >> 16));
    uint2 o;
    o.x = ((unsigned)f2bf(a1) << 16) | (unsigned)f2bf(a0);
    o.y = ((unsigned)f2bf(a3) << 16) | (unsigned)f2bf(a2);
    ((uint2*)out)[rowoff(node)] = o;
  }
}

// Layer-1 gather: fp32 x (N x 33) -> bf16 A (N x 64 ushorts, swizzled rows).
__global__ void gather_x(const float* __restrict__ x, const int* __restrict__ rowptr,
                         const int* __restrict__ srcList, unsigned short* __restrict__ out, int n) {
  const int node = blockIdx.x;
  const int lane = threadIdx.x;           // 64
  const int beg = rowptr[node], end = rowptr[node + 1];
  float acc = 0.f;
  if (lane < F_IN) acc = x[(size_t)node * F_IN + lane];
  int i = beg;
  for (; i + 3 < end; i += 4) {
    int s0 = srcList[i], s1 = srcList[i + 1], s2 = srcList[i + 2], s3 = srcList[i + 3];
    if (lane < F_IN) {
      float v0 = x[(size_t)s0 * F_IN + lane];
      float v1 = x[(size_t)s1 * F_IN + lane];
      float v2 = x[(size_t)s2 * F_IN + lane];
      float v3 = x[(size_t)s3 * F_IN + lane];
      acc += (v0 + v1) + (v2 + v3);
    }
  }
  for (; i < end; ++i) {
    if (lane < F_IN) acc += x[(size_t)srcList[i] * F_IN + lane];
  }
  out[(size_t)node * 64 + (((lane >> 3) ^ (node & 7)) << 3) + (lane & 7)] = f2bf(acc);
}

// -------- Fused GIN MLP: C = relu(relu(BN(A@W1)) @ W2 + b2), + pool ---------
// Persistent blocks (grid=256, 1 block/CU): W1,W2 staged to LDS ONCE (async),
// static tile striding. Z stays in LDS. Pool contributions accumulate in an
// LDS [64x128] buffer via ds_add_f32 (NO global atomics in the loop); each
// block writes its 32KB partial to a private slab slice at the end, summed
// later by pool_reduce. 512 thr = 8 waves: wave w -> rows (w>>1)*16..,
// cols (w&1)*64.. (4 MFMA col-tiles).

template <int K1, bool STORE>
__global__ __launch_bounds__(512, 1) void gin_mlp(
    const unsigned short* __restrict__ Ag,   // n x K1 bf16 (swizzled rows)
    const unsigned short* __restrict__ W1t,  // 128 x K1 bf16 (swizzled)
    const unsigned short* __restrict__ W2t,  // 128 x 128 bf16 (swizzled)
    const float* __restrict__ b1, const float* __restrict__ gam,
    const float* __restrict__ bet, const float* __restrict__ mu,
    const float* __restrict__ var, const float* __restrict__ b2,
    unsigned short* __restrict__ Pout,       // n x 128 bf16 (swizzled) or null
    const int* __restrict__ batch,
    float* __restrict__ slab,                // 256 x 8192 per-block partials
    int n) {
  __shared__ __align__(16) unsigned short W1ls[128 * K1];
  __shared__ __align__(16) unsigned short W2ls[128 * 128];
  __shared__ __align__(16) unsigned short Als[64 * K1];
  __shared__ __align__(16) unsigned short Zls[64 * 128];
  __shared__ __align__(16) float poolLs[GG * H];   // 32 KB
  __shared__ float sc1[128], sh1[128], b2l[128];

  const int tx = threadIdx.x;
  const int wv = tx >> 6;                 // wave 0..7
  const int lane = tx & 63;
  const int q = lane >> 4, m = lane & 15;
  const int rowGroup = (wv >> 1) * 16;    // 0,16,32,48
  const int colHalf = (wv & 1) * 64;
  const int ntiles = (n + 63) >> 6;
  const int step = gridDim.x;

  // Stage W once (async; each wave copies distinct 1024B segments).
  constexpr int W1SEG = 128 * K1 / 512;
  for (int s = wv; s < W1SEG; s += 8)
    ld_lds16(W1t + s * 512 + lane * 8, &W1ls[s * 512]);
  for (int s = wv; s < 32; s += 8)
    ld_lds16(W2t + s * 512 + lane * 8, &W2ls[s * 512]);

  // Zero LDS pool.
  {
    f32x4* pl = (f32x4*)poolLs;
    for (int i = tx; i < GG * H / 4; i += 512) pl[i] = (f32x4)(0.f);
  }
  if (tx < 128) {                          // fold bias1 into BN affine
    float s = gam[tx] * rsqrtf(var[tx] + 1e-5f);
    sc1[tx] = s;
    sh1[tx] = bet[tx] + (b1[tx] - mu[tx]) * s;
  } else if (tx < 256) {
    b2l[tx - 128] = b2[tx - 128];
  }

  int tile = blockIdx.x;
  constexpr int ASEG = 64 * K1 / 512;
  if (tile < ntiles) {
    const unsigned short* src = Ag + (size_t)tile * 64 * K1;
    for (int s = wv; s < ASEG; s += 8)
      ld_lds16(src + s * 512 + lane * 8, &Als[s * 512]);
  }
  __syncthreads();                         // drains W + A(tile)

  while (tile < ntiles) {
    // ---- GEMM1: Z = relu(BN(A @ W1 + b1)) ----
    f32x4 acc[4];
#pragma unroll
    for (int t4 = 0; t4 < 4; ++t4) acc[t4] = (f32x4)(0.f);
    const int am = rowGroup + m;
#pragma unroll
    for (int kc = 0; kc < K1 / 32; ++kc) {
      short8 af = *(const short8*)&Als[am * K1 + (((kc * 4 + q) ^ (am & 7)) << 3)];
#pragma unroll
      for (int t4 = 0; t4 < 4; ++t4) {
        const int bn = colHalf + t4 * 16 + m;
        short8 bf = *(const short8*)&W1ls[bn * K1 + (((kc * 4 + q) ^ (bn & 7)) << 3)];
        acc[t4] = __builtin_amdgcn_mfma_f32_16x16x32_bf16(af, bf, acc[t4], 0, 0, 0);
      }
    }
#pragma unroll
    for (int t4 = 0; t4 < 4; ++t4) {       // epilogue -> Zls (bf16, swizzled)
      const int col = colHalf + t4 * 16 + m;
      const float s = sc1[col], hh = sh1[col];
#pragma unroll
      for (int reg = 0; reg < 4; ++reg) {
        const int r = rowGroup + q * 4 + reg;
        float z = fmaf(acc[t4][reg], s, hh);
        z = z > 0.f ? z : 0.f;
        Zls[r * 128 + (((col >> 3) ^ (r & 7)) << 3) + (col & 7)] = f2bf(z);
      }
    }
    __syncthreads();                       // Zls ready; Als free
    const int nt = tile + step;
    if (nt < ntiles) {                     // prefetch next A, overlaps GEMM2
      const unsigned short* src = Ag + (size_t)nt * 64 * K1;
      for (int s = wv; s < ASEG; s += 8)
        ld_lds16(src + s * 512 + lane * 8, &Als[s * 512]);
    }
    // ---- GEMM2: C = relu(Z @ W2 + b2) ----
#pragma unroll
    for (int t4 = 0; t4 < 4; ++t4) acc[t4] = (f32x4)(0.f);
#pragma unroll
    for (int kc = 0; kc < 4; ++kc) {
      short8 af = *(const short8*)&Zls[am * 128 + (((kc * 4 + q) ^ (am & 7)) << 3)];
#pragma unroll
      for (int t4 = 0; t4 < 4; ++t4) {
        const int bn = colHalf + t4 * 16 + m;
        short8 bf = *(const short8*)&W2ls[bn * 128 + (((kc * 4 + q) ^ (bn & 7)) << 3)];
        acc[t4] = __builtin_amdgcn_mfma_f32_16x16x32_bf16(af, bf, acc[t4], 0, 0, 0);
      }
    }
    const int r0 = tile * 64 + rowGroup + q * 4;
    int gb4[4];
#pragma unroll
    for (int reg = 0; reg < 4; ++reg) gb4[reg] = (r0 + reg < n) ? batch[r0 + reg] : -1;
#pragma unroll
    for (int t4 = 0; t4 < 4; ++t4) {
      const int col = colHalf + t4 * 16 + m;
      float v[4];
#pragma unroll
      for (int reg = 0; reg < 4; ++reg) {
        float z = acc[t4][reg] + b2l[col];
        v[reg] = z > 0.f ? z : 0.f;
      }
      if constexpr (STORE) {
#pragma unroll
        for (int reg = 0; reg < 4; ++reg) {
          const int row = r0 + reg;
          if (row < n)
            Pout[(size_t)row * 128 + (((col >> 3) ^ (row & 7)) << 3) + (col & 7)] = f2bf(v[reg]);
        }
      }
      int gcur = -1; float ps = 0.f;       // batch sorted -> run-length flush
#pragma unroll
      for (int reg = 0; reg < 4; ++reg) {
        if (gb4[reg] < 0) break;
        if (gb4[reg] != gcur) {
          if (gcur >= 0) atomicAdd(&poolLs[gcur * H + col], ps);
          gcur = gb4[reg]; ps = v[reg];
        } else {
          ps += v[reg];
        }
      }
      if (gcur >= 0) atomicAdd(&poolLs[gcur * H + col], ps);
    }
    __syncthreads();                       // drains prefetch; Zls free
    tile = nt;
  }

  // Flush per-block pool partial to private slab slice (no contention).
  __syncthreads();
  {
    const f32x4* pl = (const f32x4*)poolLs;
    f32x4* sl = (f32x4*)(slab + (size_t)blockIdx.x * (GG * H));
    for (int i = tx; i < GG * H / 4; i += 512) sl[i] = pl[i];
  }
}

// Sum 256 per-block slabs -> pools[3][64][128]. o indexes all 3 layers.
__global__ void pool_reduce(const float* __restrict__ slab, float* __restrict__ pools) {
  const int o = blockIdx.x * 256 + threadIdx.x;    // 0 .. 3*8192-1
  const int l = o >> 13;
  const int idx = o & 8191;
  const float* s = slab + (size_t)l * 256 * (GG * H) + idx;
  float acc = 0.f;
#pragma unroll 8
  for (int b = 0; b < 256; ++b) acc += s[(size_t)b * (GG * H)];
  pools[o] = acc;
}

// ---------------- Head MLP: [G,384] -> 50 -> 20 -> 1 -> sigmoid -------------

__global__ void head_kernel(const float* __restrict__ pools,
                            const float* __restrict__ l1w, const float* __restrict__ l1b,
                            const float* __restrict__ l2w, const float* __restrict__ l2b,
                            const float* __restrict__ l3w, const float* __restrict__ l3b,
                            float* __restrict__ out) {
  const int g = blockIdx.x;
  const int t = threadIdx.x;  // 64 threads
  __shared__ float hin[3 * H];
  __shared__ float t1[50];
  __shared__ float t2[20];
  for (int idx = t; idx < 3 * H; idx += 64) {
    int l = idx >> 7, f = idx & 127;
    hin[idx] = pools[(size_t)l * GG * H + (size_t)g * H + f];
  }
  __syncthreads();
  if (t < 50) {
    float s = l1b[t];
    for (int k = 0; k < 3 * H; ++k) s = fmaf(hin[k], l1w[k * 50 + t], s);
    t1[t] = s > 0.f ? s : 0.f;
  }
  __syncthreads();
  if (t < 20) {
    float s = l2b[t];
    for (int k = 0; k < 50; ++k) s = fmaf(t1[k], l2w[k * 20 + t], s);
    t2[t] = s > 0.f ? s : 0.f;
  }
  __syncthreads();
  if (t == 0) {
    float s = l3b[0];
    for (int k = 0; k < 20; ++k) s = fmaf(t2[k], l3w[k], s);
    out[g] = 1.f / (1.f + expf(-s));
  }
}

// ---------------- launch ----------------------------------------------------

extern "C" void kernel_launch(void* const* d_in, const int* in_sizes, int n_in,
                              void* d_out, int out_size, void* d_ws, size_t ws_size,
                              hipStream_t stream) {
  const float* x    = (const float*)d_in[0];
  const int* ei     = (const int*)d_in[1];
  const int* batch  = (const int*)d_in[2];
  const int N = in_sizes[2];
  const int E = in_sizes[1] / 2;
  const int* src = ei;
  const int* dst = ei + E;

  const float* w1[3]; const float* b1[3]; const float* gm[3]; const float* be[3];
  const float* mu[3]; const float* vr[3]; const float* w2[3]; const float* b2[3];
  for (int l = 0; l < 3; ++l) {
    int b = 3 + 8 * l;
    w1[l] = (const float*)d_in[b + 0];
    b1[l] = (const float*)d_in[b + 1];
    gm[l] = (const float*)d_in[b + 2];
    be[l] = (const float*)d_in[b + 3];
    mu[l] = (const float*)d_in[b + 4];
    vr[l] = (const float*)d_in[b + 5];
    w2[l] = (const float*)d_in[b + 6];
    b2[l] = (const float*)d_in[b + 7];
  }
  const float* l1w = (const float*)d_in[27];
  const float* l1b = (const float*)d_in[28];
  const float* l2w = (const float*)d_in[29];
  const float* l2b = (const float*)d_in[30];
  const float* l3w = (const float*)d_in[31];
  const float* l3b = (const float*)d_in[32];

  // workspace carve-up
  char* ws = (char*)d_ws;
  size_t off = 0;
  auto take = [&](size_t bytes) {
    size_t p = off;
    off += (bytes + 255) & ~(size_t)255;
    return p;
  };
  unsigned short* A = (unsigned short*)(ws + take((size_t)N * H * 2));  // agg (bf16, swizzled)
  unsigned short* P = (unsigned short*)(ws + take((size_t)N * H * 2));  // layer out (bf16, swizzled)
  float* pools  = (float*)(ws + take((size_t)3 * GG * H * 4));
  float* slab   = (float*)(ws + take((size_t)3 * 256 * GG * H * 4));    // 24 MB partials
  int* rowptr   = (int*)(ws + take((size_t)(N + 1) * 4));
  int* cursor   = (int*)(ws + take((size_t)N * 4));
  int* srcList  = (int*)(ws + take((size_t)E * 4));
  int* partial  = (int*)(ws + take((size_t)1024 * 4));
  unsigned short* Wt[6];
  for (int i = 0; i < 6; ++i) Wt[i] = (unsigned short*)(ws + take((size_t)H * H * 2));
  (void)ws_size; (void)n_in; (void)out_size;

  const int eb = (E + 255) / 256;
  const int nb = (N + 1023) / 1024;

  hipMemsetAsync(cursor, 0, (size_t)N * 4, stream);

  // W transpose+convert+swizzle (all 6 in one launch)
  WConvArgs wa;
  wa.w[0] = w1[0]; wa.K[0] = F_IN; wa.Kp[0] = 64;
  wa.w[1] = w2[0]; wa.K[1] = H;    wa.Kp[1] = H;
  wa.w[2] = w1[1]; wa.K[2] = H;    wa.Kp[2] = H;
  wa.w[3] = w2[1]; wa.K[3] = H;    wa.Kp[3] = H;
  wa.w[4] = w1[2]; wa.K[4] = H;    wa.Kp[4] = H;
  wa.w[5] = w2[2]; wa.K[5] = H;    wa.Kp[5] = H;
  for (int i = 0; i < 6; ++i) wa.o[i] = Wt[i];
  wconv<<<dim3((H * H + 255) / 256, 6), 256, 0, stream>>>(wa);

  // CSR by dst
  hist_kernel<<<eb, 256, 0, stream>>>(dst, cursor, E);
  block_reduce<<<nb, 256, 0, stream>>>(cursor, partial, N);
  scan_partials<<<1, 256, 0, stream>>>(partial, nb, rowptr + N);
  block_scan<<<nb, 256, 0, stream>>>(cursor, partial, rowptr, N);
  build_kernel<<<eb, 256, 0, stream>>>(src, dst, cursor, srcList, E);

  // ---- layer 1 (K padded 33 -> 64) ----
  gather_x<<<N, 64, 0, stream>>>(x, rowptr, srcList, A, N);
  gin_mlp<64, true><<<256, 512, 0, stream>>>(
      A, Wt[0], Wt[1], b1[0], gm[0], be[0], mu[0], vr[0], b2[0],
      P, batch, slab, N);

  // ---- layer 2 ----
  gather_h<<<N, 64, 0, stream>>>(P, rowptr, srcList, A, N);
  gin_mlp<128, true><<<256, 512, 0, stream>>>(
      A, Wt[2], Wt[3], b1[1], gm[1], be[1], mu[1], vr[1], b2[1],
      P, batch, slab + (size_t)256 * GG * H, N);

  // ---- layer 3 (h3 pooled only) ----
  gather_h<<<N, 64, 0, stream>>>(P, rowptr, srcList, A, N);
  gin_mlp<128, false><<<256, 512, 0, stream>>>(
      A, Wt[4], Wt[5], b1[2], gm[2], be[2], mu[2], vr[2], b2[2],
      nullptr, batch, slab + (size_t)2 * 256 * GG * H, N);

  // ---- pool reduce + head ----
  pool_reduce<<<3 * GG * H / 256, 256, 0, stream>>>(slab, pools);
  head_kernel<<<GG, 64, 0, stream>>>(pools, l1w, l1b, l2w, l2b, l3w, l3b, (float*)d_out);
}

// Round 7
// 345.554 us; speedup vs baseline: 1.4272x; 1.1596x over previous
//
#include <hip/hip_runtime.h>
#include <math.h>

// N=50000 nodes, E=800000 edges, F_IN=33, H=128, G=64 graphs.
static constexpr int F_IN = 33;
static constexpr int H    = 128;
static constexpr int GG   = 64;

typedef __attribute__((ext_vector_type(8))) short short8;
typedef __attribute__((ext_vector_type(4))) float f32x4;

__device__ __forceinline__ unsigned short f2bf(float f) {
  union { float f; unsigned u; } v; v.f = f;
  unsigned r = v.u + 0x7fffu + ((v.u >> 16) & 1u);   // RNE
  return (unsigned short)(r >> 16);
}
__device__ __forceinline__ float bf2f(unsigned short b) {
  union { unsigned u; float f; } v; v.u = ((unsigned)b) << 16;
  return v.f;
}

// Async global->LDS copy, 16B per lane, wave-uniform LDS base (lane-linear).
using gas_u32 = const __attribute__((address_space(1))) unsigned int*;
using las_u32 = __attribute__((address_space(3))) unsigned int*;
__device__ __forceinline__ void ld_lds16(const unsigned short* g, unsigned short* l) {
  __builtin_amdgcn_global_load_lds((gas_u32)(const void*)g, (las_u32)(void*)l, 16, 0, 0);
}

// ---------------- CSR build: bucketed counting sort (XCD-local writes) ------
// Bucket = dst >> 8 (256 nodes/bucket, NB = ceil(N/256) <= 256).
// p1: per-(bucket,block) LDS hist -> M.   scan(M) -> global offsets.
// p2: scatter (src,dst) into bucket-partitioned tmp via LDS cursors.
// p3: one block per bucket: exact hist + scan -> rowptr, scatter srcList
//     into a block-private contiguous segment.

__global__ void csr_p1(const int* __restrict__ dst, int* __restrict__ M, int E, int NB) {
  __shared__ int hist[256];
  const int tx = threadIdx.x, blk = blockIdx.x, nblk = gridDim.x;
  for (int i = tx; i < NB; i += 256) hist[i] = 0;
  __syncthreads();
  const int chunk = (E + nblk - 1) / nblk;
  const int lo = blk * chunk;
  const int hi = min(lo + chunk, E);
  for (int i = lo + tx; i < hi; i += 256)
    atomicAdd(&hist[dst[i] >> 8], 1);
  __syncthreads();
  for (int b = tx; b < NB; b += 256)
    M[b * nblk + blk] = hist[b];
}

__global__ void csr_p2(const int* __restrict__ src, const int* __restrict__ dst,
                       const int* __restrict__ Mscan, int2* __restrict__ tmp,
                       int E, int NB) {
  __shared__ int cur[256];
  const int tx = threadIdx.x, blk = blockIdx.x, nblk = gridDim.x;
  for (int b = tx; b < NB; b += 256) cur[b] = Mscan[b * nblk + blk];
  __syncthreads();
  const int chunk = (E + nblk - 1) / nblk;
  const int lo = blk * chunk;
  const int hi = min(lo + chunk, E);
  for (int i = lo + tx; i < hi; i += 256) {
    int d = dst[i];
    int pos = atomicAdd(&cur[d >> 8], 1);
    tmp[pos] = make_int2(src[i], d);
  }
}

__global__ void csr_p3(const int2* __restrict__ tmp, const int* __restrict__ Mscan,
                       int* __restrict__ rowptr, int* __restrict__ srcList,
                       int n, int E, int NB, int NBLK) {
  __shared__ int hist[256];
  __shared__ int scn[256];
  const int b = blockIdx.x, tx = threadIdx.x;
  const int segStart = Mscan[b * NBLK];
  const int segEnd = (b + 1 < NB) ? Mscan[(b + 1) * NBLK] : E;
  const int nodeBase = b << 8;
  hist[tx] = 0;
  __syncthreads();
  for (int i = segStart + tx; i < segEnd; i += 256)
    atomicAdd(&hist[tmp[i].y - nodeBase], 1);
  __syncthreads();
  int v = hist[tx];
  scn[tx] = v;
  __syncthreads();
  for (int off = 1; off < 256; off <<= 1) {
    int add = (tx >= off) ? scn[tx - off] : 0;
    __syncthreads();
    scn[tx] += add;
    __syncthreads();
  }
  int ex = scn[tx] - v;                    // exclusive prefix
  if (nodeBase + tx < n) rowptr[nodeBase + tx] = segStart + ex;
  hist[tx] = ex;                           // reuse as cursor
  __syncthreads();
  for (int i = segStart + tx; i < segEnd; i += 256) {
    int2 e = tmp[i];
    int pos = atomicAdd(&hist[e.y - nodeBase], 1);
    srcList[segStart + pos] = e.x;
  }
}

// ---------------- Hierarchical exclusive scan (reused for M) ----------------

__global__ void block_reduce(const int* __restrict__ cnt, int* __restrict__ partial, int n) {
  __shared__ int s[256];
  const int t = threadIdx.x;
  const int base = blockIdx.x * 1024;
  int sum = 0;
  for (int i = t; i < 1024; i += 256) {
    int idx = base + i;
    if (idx < n) sum += cnt[idx];
  }
  s[t] = sum;
  __syncthreads();
  for (int off = 128; off > 0; off >>= 1) {
    if (t < off) s[t] += s[t + off];
    __syncthreads();
  }
  if (t == 0) partial[blockIdx.x] = s[0];
}

__global__ void scan_partials(int* __restrict__ partial, int nb, int* __restrict__ total_out) {
  __shared__ int s[256];
  const int t = threadIdx.x;
  int carry = 0;
  for (int base = 0; base < nb; base += 256) {
    int v = (base + t < nb) ? partial[base + t] : 0;
    s[t] = v;
    __syncthreads();
    for (int off = 1; off < 256; off <<= 1) {
      int add = (t >= off) ? s[t - off] : 0;
      __syncthreads();
      s[t] += add;
      __syncthreads();
    }
    if (base + t < nb) partial[base + t] = s[t] - v + carry;
    carry += s[255];
    __syncthreads();
  }
  if (t == 0) *total_out = carry;
}

// In-place-capable: reads all 4 elements before writing.
__global__ void block_scan(int* __restrict__ cnt_cursor, const int* __restrict__ partial,
                           int* __restrict__ outArr, int n) {
  __shared__ int s[256];
  const int t = threadIdx.x;
  const int base = blockIdx.x * 1024;
  int v[4];
  int sum = 0;
#pragma unroll
  for (int j = 0; j < 4; ++j) {
    int idx = base + t * 4 + j;
    v[j] = (idx < n) ? cnt_cursor[idx] : 0;
    sum += v[j];
  }
  s[t] = sum;
  __syncthreads();
  for (int off = 1; off < 256; off <<= 1) {
    int add = (t >= off) ? s[t - off] : 0;
    __syncthreads();
    s[t] += add;
    __syncthreads();
  }
  int excl = s[t] - sum + partial[blockIdx.x];
#pragma unroll
  for (int j = 0; j < 4; ++j) {
    int idx = base + t * 4 + j;
    if (idx < n) {
      outArr[idx] = excl;
      cnt_cursor[idx] = excl;
    }
    excl += v[j];
  }
}

// ------- W transpose+convert to bf16, XOR-swizzled 16B chunks per row -------
// o[n][ (chunk^ (n&7))*8 + k%8 ] = W[k][n]; chunk = k/8. K zero-padded to Kp.

struct WConvArgs {
  const float* w[6];
  unsigned short* o[6];
  int K[6], Kp[6];
};

__global__ void wconv(WConvArgs a) {
  const int wi = blockIdx.y;
  const int i = blockIdx.x * 256 + threadIdx.x;
  const int Kp = a.Kp[wi];
  if (i >= H * Kp) return;
  const int nn = i / Kp, k = i - nn * Kp;
  float v = (k < a.K[wi]) ? a.w[wi][(size_t)k * H + nn] : 0.f;
  a.o[wi][(size_t)nn * Kp + (((k >> 3) ^ (nn & 7)) << 3) + (k & 7)] = f2bf(v);
}

// ---------------- Aggregation (gather), bf16 h, swizzled rows ---------------
// Row r = 256B = 32 uint2; logical dword d lives at ((d>>2)^(r&7))*4 + (d&3).
// Two edges per vmem instruction: lanes 0-31 -> edge i, lanes 32-63 -> edge
// i+1, each lane one uint2 (4 bf16 features). Final cross-half combine via
// __shfl_down(.,32); lanes 0-31 add self and store.

__global__ void gather_h(const unsigned short* __restrict__ h, const int* __restrict__ rowptr,
                         const int* __restrict__ srcList, unsigned short* __restrict__ out, int n) {
  const int node = blockIdx.x;
  const int lane = threadIdx.x;           // 64
  const int half = lane >> 5;             // which edge of the pair
  const int l32 = lane & 31;
  const uint2* h4 = (const uint2*)h;      // row = 32 uint2
  const int c4 = l32 >> 1, p1 = l32 & 1;  // 16B chunk, uint2 parity in chunk
  auto rowoff = [&](int r) { return (size_t)r * 32 + (((c4 ^ (r & 7)) << 1) | p1); };

  const int beg = rowptr[node], end = rowptr[node + 1];
  float a0 = 0.f, a1 = 0.f, a2 = 0.f, a3 = 0.f;
  int i = beg;
  for (; i + 7 < end; i += 8) {
    int s0 = srcList[i + half];
    int s1 = srcList[i + 2 + half];
    int s2 = srcList[i + 4 + half];
    int s3 = srcList[i + 6 + half];
    uint2 v0 = h4[rowoff(s0)];
    uint2 v1 = h4[rowoff(s1)];
    uint2 v2 = h4[rowoff(s2)];
    uint2 v3 = h4[rowoff(s3)];
    a0 += (bf2f((unsigned short)v0.x) + bf2f((unsigned short)v1.x)) +
          (bf2f((unsigned short)v2.x) + bf2f((unsigned short)v3.x));
    a1 += (bf2f((unsigned short)(v0.x >> 16)) + bf2f((unsigned short)(v1.x >> 16))) +
          (bf2f((unsigned short)(v2.x >> 16)) + bf2f((unsigned short)(v3.x >> 16)));
    a2 += (bf2f((unsigned short)v0.y) + bf2f((unsigned short)v1.y)) +
          (bf2f((unsigned short)v2.y) + bf2f((unsigned short)v3.y));
    a3 += (bf2f((unsigned short)(v0.y >> 16)) + bf2f((unsigned short)(v1.y >> 16))) +
          (bf2f((unsigned short)(v2.y >> 16)) + bf2f((unsigned short)(v3.y >> 16)));
  }
  for (; i + 1 < end; i += 2) {
    int s0 = srcList[i + half];
    uint2 v = h4[rowoff(s0)];
    a0 += bf2f((unsigned short)v.x);
    a1 += bf2f((unsigned short)(v.x >> 16));
    a2 += bf2f((unsigned short)v.y);
    a3 += bf2f((unsigned short)(v.y >> 16));
  }
  if (i < end && half == 0) {             // odd tail, half 0 only
    int s0 = srcList[i];
    uint2 v = h4[rowoff(s0)];
    a0 += bf2f((unsigned short)v.x);
    a1 += bf2f((unsigned short)(v.x >> 16));
    a2 += bf2f((unsigned short)v.y);
    a3 += bf2f((unsigned short)(v.y >> 16));
  }
  // combine halves (lane gets lane+32's accumulators)
  float b0 = __shfl_down(a0, 32), b1 = __shfl_down(a1, 32);
  float b2 = __shfl_down(a2, 32), b3 = __shfl_down(a3, 32);
  if (half == 0) {
    uint2 sv = h4[rowoff(node)];
    a0 += b0 + bf2f((unsigned short)sv.x);
    a1 += b1 + bf2f((unsigned short)(sv.x >> 16));
    a2 += b2 + bf2f((unsigned short)sv.y);
    a3 += b3 + bf2f((unsigned short)(sv.y >> 16));
    uint2 o;
    o.x = ((unsigned)f2bf(a1) << 16) | (unsigned)f2bf(a0);
    o.y = ((unsigned)f2bf(a3) << 16) | (unsigned)f2bf(a2);
    ((uint2*)out)[rowoff(node)] = o;
  }
}

// Layer-1 gather: fp32 x (N x 33) -> bf16 A (N x 64 ushorts, swizzled rows).
__global__ void gather_x(const float* __restrict__ x, const int* __restrict__ rowptr,
                         const int* __restrict__ srcList, unsigned short* __restrict__ out, int n) {
  const int node = blockIdx.x;
  const int lane = threadIdx.x;           // 64
  const int beg = rowptr[node], end = rowptr[node + 1];
  float acc = 0.f;
  if (lane < F_IN) acc = x[(size_t)node * F_IN + lane];
  int i = beg;
  for (; i + 3 < end; i += 4) {
    int s0 = srcList[i], s1 = srcList[i + 1], s2 = srcList[i + 2], s3 = srcList[i + 3];
    if (lane < F_IN) {
      float v0 = x[(size_t)s0 * F_IN + lane];
      float v1 = x[(size_t)s1 * F_IN + lane];
      float v2 = x[(size_t)s2 * F_IN + lane];
      float v3 = x[(size_t)s3 * F_IN + lane];
      acc += (v0 + v1) + (v2 + v3);
    }
  }
  for (; i < end; ++i) {
    if (lane < F_IN) acc += x[(size_t)srcList[i] * F_IN + lane];
  }
  out[(size_t)node * 64 + (((lane >> 3) ^ (node & 7)) << 3) + (lane & 7)] = f2bf(acc);
}

// -------- Fused GIN MLP: C = relu(relu(BN(A@W1)) @ W2 + b2), + pool ---------
// Persistent blocks (grid=256, 1 block/CU): W1,W2 staged to LDS ONCE (async),
// static tile striding. Z stays in LDS. Pool contributions accumulate in an
// LDS [64x128] buffer (no global atomics in the loop); each block writes its
// 32KB partial to a private slab slice at the end, summed by pool_reduce.

template <int K1, bool STORE>
__global__ __launch_bounds__(512, 1) void gin_mlp(
    const unsigned short* __restrict__ Ag,   // n x K1 bf16 (swizzled rows)
    const unsigned short* __restrict__ W1t,  // 128 x K1 bf16 (swizzled)
    const unsigned short* __restrict__ W2t,  // 128 x 128 bf16 (swizzled)
    const float* __restrict__ b1, const float* __restrict__ gam,
    const float* __restrict__ bet, const float* __restrict__ mu,
    const float* __restrict__ var, const float* __restrict__ b2,
    unsigned short* __restrict__ Pout,       // n x 128 bf16 (swizzled) or null
    const int* __restrict__ batch,
    float* __restrict__ slab,                // 256 x 8192 per-block partials
    int n) {
  __shared__ __align__(16) unsigned short W1ls[128 * K1];
  __shared__ __align__(16) unsigned short W2ls[128 * 128];
  __shared__ __align__(16) unsigned short Als[64 * K1];
  __shared__ __align__(16) unsigned short Zls[64 * 128];
  __shared__ __align__(16) float poolLs[GG * H];   // 32 KB
  __shared__ float sc1[128], sh1[128], b2l[128];

  const int tx = threadIdx.x;
  const int wv = tx >> 6;                 // wave 0..7
  const int lane = tx & 63;
  const int q = lane >> 4, m = lane & 15;
  const int rowGroup = (wv >> 1) * 16;    // 0,16,32,48
  const int colHalf = (wv & 1) * 64;
  const int ntiles = (n + 63) >> 6;
  const int step = gridDim.x;

  // Stage W once (async; each wave copies distinct 1024B segments).
  constexpr int W1SEG = 128 * K1 / 512;
  for (int s = wv; s < W1SEG; s += 8)
    ld_lds16(W1t + s * 512 + lane * 8, &W1ls[s * 512]);
  for (int s = wv; s < 32; s += 8)
    ld_lds16(W2t + s * 512 + lane * 8, &W2ls[s * 512]);

  // Zero LDS pool.
  {
    f32x4* pl = (f32x4*)poolLs;
    for (int i = tx; i < GG * H / 4; i += 512) pl[i] = (f32x4)(0.f);
  }
  if (tx < 128) {                          // fold bias1 into BN affine
    float s = gam[tx] * rsqrtf(var[tx] + 1e-5f);
    sc1[tx] = s;
    sh1[tx] = bet[tx] + (b1[tx] - mu[tx]) * s;
  } else if (tx < 256) {
    b2l[tx - 128] = b2[tx - 128];
  }

  int tile = blockIdx.x;
  constexpr int ASEG = 64 * K1 / 512;
  if (tile < ntiles) {
    const unsigned short* src = Ag + (size_t)tile * 64 * K1;
    for (int s = wv; s < ASEG; s += 8)
      ld_lds16(src + s * 512 + lane * 8, &Als[s * 512]);
  }
  __syncthreads();                         // drains W + A(tile)

  while (tile < ntiles) {
    // ---- GEMM1: Z = relu(BN(A @ W1 + b1)) ----
    f32x4 acc[4];
#pragma unroll
    for (int t4 = 0; t4 < 4; ++t4) acc[t4] = (f32x4)(0.f);
    const int am = rowGroup + m;
#pragma unroll
    for (int kc = 0; kc < K1 / 32; ++kc) {
      short8 af = *(const short8*)&Als[am * K1 + (((kc * 4 + q) ^ (am & 7)) << 3)];
#pragma unroll
      for (int t4 = 0; t4 < 4; ++t4) {
        const int bn = colHalf + t4 * 16 + m;
        short8 bf = *(const short8*)&W1ls[bn * K1 + (((kc * 4 + q) ^ (bn & 7)) << 3)];
        acc[t4] = __builtin_amdgcn_mfma_f32_16x16x32_bf16(af, bf, acc[t4], 0, 0, 0);
      }
    }
#pragma unroll
    for (int t4 = 0; t4 < 4; ++t4) {       // epilogue -> Zls (bf16, swizzled)
      const int col = colHalf + t4 * 16 + m;
      const float s = sc1[col], hh = sh1[col];
#pragma unroll
      for (int reg = 0; reg < 4; ++reg) {
        const int r = rowGroup + q * 4 + reg;
        float z = fmaf(acc[t4][reg], s, hh);
        z = z > 0.f ? z : 0.f;
        Zls[r * 128 + (((col >> 3) ^ (r & 7)) << 3) + (col & 7)] = f2bf(z);
      }
    }
    __syncthreads();                       // Zls ready; Als free
    const int nt = tile + step;
    if (nt < ntiles) {                     // prefetch next A, overlaps GEMM2
      const unsigned short* src = Ag + (size_t)nt * 64 * K1;
      for (int s = wv; s < ASEG; s += 8)
        ld_lds16(src + s * 512 + lane * 8, &Als[s * 512]);
    }
    // ---- GEMM2: C = relu(Z @ W2 + b2) ----
#pragma unroll
    for (int t4 = 0; t4 < 4; ++t4) acc[t4] = (f32x4)(0.f);
#pragma unroll
    for (int kc = 0; kc < 4; ++kc) {
      short8 af = *(const short8*)&Zls[am * 128 + (((kc * 4 + q) ^ (am & 7)) << 3)];
#pragma unroll
      for (int t4 = 0; t4 < 4; ++t4) {
        const int bn = colHalf + t4 * 16 + m;
        short8 bf = *(const short8*)&W2ls[bn * 128 + (((kc * 4 + q) ^ (bn & 7)) << 3)];
        acc[t4] = __builtin_amdgcn_mfma_f32_16x16x32_bf16(af, bf, acc[t4], 0, 0, 0);
      }
    }
    const int r0 = tile * 64 + rowGroup + q * 4;
    int gb4[4];
#pragma unroll
    for (int reg = 0; reg < 4; ++reg) gb4[reg] = (r0 + reg < n) ? batch[r0 + reg] : -1;
#pragma unroll
    for (int t4 = 0; t4 < 4; ++t4) {
      const int col = colHalf + t4 * 16 + m;
      float v[4];
#pragma unroll
      for (int reg = 0; reg < 4; ++reg) {
        float z = acc[t4][reg] + b2l[col];
        v[reg] = z > 0.f ? z : 0.f;
      }
      if constexpr (STORE) {
#pragma unroll
        for (int reg = 0; reg < 4; ++reg) {
          const int row = r0 + reg;
          if (row < n)
            Pout[(size_t)row * 128 + (((col >> 3) ^ (row & 7)) << 3) + (col & 7)] = f2bf(v[reg]);
        }
      }
      int gcur = -1; float ps = 0.f;       // batch sorted -> run-length flush
#pragma unroll
      for (int reg = 0; reg < 4; ++reg) {
        if (gb4[reg] < 0) break;
        if (gb4[reg] != gcur) {
          if (gcur >= 0) atomicAdd(&poolLs[gcur * H + col], ps);
          gcur = gb4[reg]; ps = v[reg];
        } else {
          ps += v[reg];
        }
      }
      if (gcur >= 0) atomicAdd(&poolLs[gcur * H + col], ps);
    }
    __syncthreads();                       // drains prefetch; Zls free
    tile = nt;
  }

  // Flush per-block pool partial to private slab slice (no contention).
  __syncthreads();
  {
    const f32x4* pl = (const f32x4*)poolLs;
    f32x4* sl = (f32x4*)(slab + (size_t)blockIdx.x * (GG * H));
    for (int i = tx; i < GG * H / 4; i += 512) sl[i] = pl[i];
  }
}

// Sum 256 per-block slabs -> pools[3][64][128]. o indexes all 3 layers.
__global__ void pool_reduce(const float* __restrict__ slab, float* __restrict__ pools) {
  const int o = blockIdx.x * 256 + threadIdx.x;    // 0 .. 3*8192-1
  const int l = o >> 13;
  const int idx = o & 8191;
  const float* s = slab + (size_t)l * 256 * (GG * H) + idx;
  float acc = 0.f;
#pragma unroll 8
  for (int b = 0; b < 256; ++b) acc += s[(size_t)b * (GG * H)];
  pools[o] = acc;
}

// ---------------- Head MLP: [G,384] -> 50 -> 20 -> 1 -> sigmoid -------------

__global__ void head_kernel(const float* __restrict__ pools,
                            const float* __restrict__ l1w, const float* __restrict__ l1b,
                            const float* __restrict__ l2w, const float* __restrict__ l2b,
                            const float* __restrict__ l3w, const float* __restrict__ l3b,
                            float* __restrict__ out) {
  const int g = blockIdx.x;
  const int t = threadIdx.x;  // 64 threads
  __shared__ float hin[3 * H];
  __shared__ float t1[50];
  __shared__ float t2[20];
  for (int idx = t; idx < 3 * H; idx += 64) {
    int l = idx >> 7, f = idx & 127;
    hin[idx] = pools[(size_t)l * GG * H + (size_t)g * H + f];
  }
  __syncthreads();
  if (t < 50) {
    float s = l1b[t];
    for (int k = 0; k < 3 * H; ++k) s = fmaf(hin[k], l1w[k * 50 + t], s);
    t1[t] = s > 0.f ? s : 0.f;
  }
  __syncthreads();
  if (t < 20) {
    float s = l2b[t];
    for (int k = 0; k < 50; ++k) s = fmaf(t1[k], l2w[k * 20 + t], s);
    t2[t] = s > 0.f ? s : 0.f;
  }
  __syncthreads();
  if (t == 0) {
    float s = l3b[0];
    for (int k = 0; k < 20; ++k) s = fmaf(t2[k], l3w[k], s);
    out[g] = 1.f / (1.f + expf(-s));
  }
}

// ---------------- launch ----------------------------------------------------

extern "C" void kernel_launch(void* const* d_in, const int* in_sizes, int n_in,
                              void* d_out, int out_size, void* d_ws, size_t ws_size,
                              hipStream_t stream) {
  const float* x    = (const float*)d_in[0];
  const int* ei     = (const int*)d_in[1];
  const int* batch  = (const int*)d_in[2];
  const int N = in_sizes[2];
  const int E = in_sizes[1] / 2;
  const int* src = ei;
  const int* dst = ei + E;

  const float* w1[3]; const float* b1[3]; const float* gm[3]; const float* be[3];
  const float* mu[3]; const float* vr[3]; const float* w2[3]; const float* b2[3];
  for (int l = 0; l < 3; ++l) {
    int b = 3 + 8 * l;
    w1[l] = (const float*)d_in[b + 0];
    b1[l] = (const float*)d_in[b + 1];
    gm[l] = (const float*)d_in[b + 2];
    be[l] = (const float*)d_in[b + 3];
    mu[l] = (const float*)d_in[b + 4];
    vr[l] = (const float*)d_in[b + 5];
    w2[l] = (const float*)d_in[b + 6];
    b2[l] = (const float*)d_in[b + 7];
  }
  const float* l1w = (const float*)d_in[27];
  const float* l1b = (const float*)d_in[28];
  const float* l2w = (const float*)d_in[29];
  const float* l2b = (const float*)d_in[30];
  const float* l3w = (const float*)d_in[31];
  const float* l3b = (const float*)d_in[32];

  // workspace carve-up
  char* ws = (char*)d_ws;
  size_t off = 0;
  auto take = [&](size_t bytes) {
    size_t p = off;
    off += (bytes + 255) & ~(size_t)255;
    return p;
  };
  unsigned short* A = (unsigned short*)(ws + take((size_t)N * H * 2));  // agg (bf16, swizzled)
  unsigned short* P = (unsigned short*)(ws + take((size_t)N * H * 2));  // layer out (bf16, swizzled)
  float* pools  = (float*)(ws + take((size_t)3 * GG * H * 4));
  float* slab   = (float*)(ws + take((size_t)3 * 256 * GG * H * 4));    // 24 MB partials
  int* rowptr   = (int*)(ws + take((size_t)(N + 1) * 4));
  int* M        = (int*)(ws + take((size_t)256 * 256 * 4));             // bucket counts/offsets
  int* srcList  = (int*)(ws + take((size_t)E * 4));
  int2* tmp     = (int2*)(ws + take((size_t)E * 8));                    // bucketed (src,dst)
  int* partial  = (int*)(ws + take((size_t)1024 * 4));
  unsigned short* Wt[6];
  for (int i = 0; i < 6; ++i) Wt[i] = (unsigned short*)(ws + take((size_t)H * H * 2));
  (void)ws_size; (void)n_in; (void)out_size;

  const int NBLK = 256;
  const int NB = (N + 255) >> 8;          // buckets of 256 nodes (<= 256)
  const int nscan = NB * NBLK;
  const int nb = (nscan + 1023) / 1024;

  // W transpose+convert+swizzle (all 6 in one launch)
  WConvArgs wa;
  wa.w[0] = w1[0]; wa.K[0] = F_IN; wa.Kp[0] = 64;
  wa.w[1] = w2[0]; wa.K[1] = H;    wa.Kp[1] = H;
  wa.w[2] = w1[1]; wa.K[2] = H;    wa.Kp[2] = H;
  wa.w[3] = w2[1]; wa.K[3] = H;    wa.Kp[3] = H;
  wa.w[4] = w1[2]; wa.K[4] = H;    wa.Kp[4] = H;
  wa.w[5] = w2[2]; wa.K[5] = H;    wa.Kp[5] = H;
  for (int i = 0; i < 6; ++i) wa.o[i] = Wt[i];
  wconv<<<dim3((H * H + 255) / 256, 6), 256, 0, stream>>>(wa);

  // CSR by dst: bucketed counting sort
  csr_p1<<<NBLK, 256, 0, stream>>>(dst, M, E, NB);
  block_reduce<<<nb, 256, 0, stream>>>(M, partial, nscan);
  scan_partials<<<1, 256, 0, stream>>>(partial, nb, rowptr + N);
  block_scan<<<nb, 256, 0, stream>>>(M, partial, M, nscan);   // in-place scan
  csr_p2<<<NBLK, 256, 0, stream>>>(src, dst, M, tmp, E, NB);
  csr_p3<<<NB, 256, 0, stream>>>(tmp, M, rowptr, srcList, N, E, NB, NBLK);

  // ---- layer 1 (K padded 33 -> 64) ----
  gather_x<<<N, 64, 0, stream>>>(x, rowptr, srcList, A, N);
  gin_mlp<64, true><<<256, 512, 0, stream>>>(
      A, Wt[0], Wt[1], b1[0], gm[0], be[0], mu[0], vr[0], b2[0],
      P, batch, slab, N);

  // ---- layer 2 ----
  gather_h<<<N, 64, 0, stream>>>(P, rowptr, srcList, A, N);
  gin_mlp<128, true><<<256, 512, 0, stream>>>(
      A, Wt[2], Wt[3], b1[1], gm[1], be[1], mu[1], vr[1], b2[1],
      P, batch, slab + (size_t)256 * GG * H, N);

  // ---- layer 3 (h3 pooled only) ----
  gather_h<<<N, 64, 0, stream>>>(P, rowptr, srcList, A, N);
  gin_mlp<128, false><<<256, 512, 0, stream>>>(
      A, Wt[4], Wt[5], b1[2], gm[2], be[2], mu[2], vr[2], b2[2],
      nullptr, batch, slab + (size_t)2 * 256 * GG * H, N);

  // ---- pool reduce + head ----
  pool_reduce<<<3 * GG * H / 256, 256, 0, stream>>>(slab, pools);
  head_kernel<<<GG, 64, 0, stream>>>(pools, l1w, l1b, l2w, l2b, l3w, l3b, (float*)d_out);
}

// Round 8
// 341.319 us; speedup vs baseline: 1.4449x; 1.0124x over previous
//
#include <hip/hip_runtime.h>
#include <math.h>

// N=50000 nodes, E=800000 edges, F_IN=33, H=128, G=64 graphs.
static constexpr int F_IN = 33;
static constexpr int H    = 128;
static constexpr int GG   = 64;

typedef __attribute__((ext_vector_type(8))) short short8;
typedef __attribute__((ext_vector_type(4))) float f32x4;

__device__ __forceinline__ unsigned short f2bf(float f) {
  union { float f; unsigned u; } v; v.f = f;
  unsigned r = v.u + 0x7fffu + ((v.u >> 16) & 1u);   // RNE
  return (unsigned short)(r >> 16);
}
__device__ __forceinline__ float bf2f(unsigned short b) {
  union { unsigned u; float f; } v; v.u = ((unsigned)b) << 16;
  return v.f;
}

// Async global->LDS copy, 16B per lane, wave-uniform LDS base (lane-linear).
using gas_u32 = const __attribute__((address_space(1))) unsigned int*;
using las_u32 = __attribute__((address_space(3))) unsigned int*;
__device__ __forceinline__ void ld_lds16(const unsigned short* g, unsigned short* l) {
  __builtin_amdgcn_global_load_lds((gas_u32)(const void*)g, (las_u32)(void*)l, 16, 0, 0);
}

// ---------------- CSR build: bucketed counting sort (XCD-local writes) ------
// Bucket = dst >> 8 (256 nodes/bucket). p1: per-(bucket,block) LDS hist -> M.
// scan(M) -> offsets. p2: scatter packed (src<<8 | dst&255) into bucketed tmp.
// p3: per bucket: exact hist + scan -> rowptr, scatter srcList contiguously.

__global__ void csr_p1(const int* __restrict__ dst, int* __restrict__ M, int E, int NB) {
  __shared__ int hist[256];
  const int tx = threadIdx.x, blk = blockIdx.x, nblk = gridDim.x;
  for (int i = tx; i < NB; i += 256) hist[i] = 0;
  __syncthreads();
  const int chunk = (E + nblk - 1) / nblk;
  const int lo = blk * chunk;
  const int hi = min(lo + chunk, E);
  for (int i = lo + tx; i < hi; i += 256)
    atomicAdd(&hist[dst[i] >> 8], 1);
  __syncthreads();
  for (int b = tx; b < NB; b += 256)
    M[b * nblk + blk] = hist[b];
}

__global__ void csr_p2(const int* __restrict__ src, const int* __restrict__ dst,
                       const int* __restrict__ Mscan, unsigned* __restrict__ tmp,
                       int E, int NB) {
  __shared__ int cur[256];
  const int tx = threadIdx.x, blk = blockIdx.x, nblk = gridDim.x;
  for (int b = tx; b < NB; b += 256) cur[b] = Mscan[b * nblk + blk];
  __syncthreads();
  const int chunk = (E + nblk - 1) / nblk;
  const int lo = blk * chunk;
  const int hi = min(lo + chunk, E);
  for (int i = lo + tx; i < hi; i += 256) {
    int d = dst[i];
    int pos = atomicAdd(&cur[d >> 8], 1);
    tmp[pos] = ((unsigned)src[i] << 8) | (unsigned)(d & 255);   // src < 2^24
  }
}

__global__ void csr_p3(const unsigned* __restrict__ tmp, const int* __restrict__ Mscan,
                       int* __restrict__ rowptr, int* __restrict__ srcList,
                       int n, int E, int NB, int NBLK) {
  __shared__ int hist[256];
  __shared__ int scn[256];
  const int b = blockIdx.x, tx = threadIdx.x;
  const int segStart = Mscan[b * NBLK];
  const int segEnd = (b + 1 < NB) ? Mscan[(b + 1) * NBLK] : E;
  const int nodeBase = b << 8;
  hist[tx] = 0;
  __syncthreads();
  for (int i = segStart + tx; i < segEnd; i += 256)
    atomicAdd(&hist[tmp[i] & 255u], 1);
  __syncthreads();
  int v = hist[tx];
  scn[tx] = v;
  __syncthreads();
  for (int off = 1; off < 256; off <<= 1) {
    int add = (tx >= off) ? scn[tx - off] : 0;
    __syncthreads();
    scn[tx] += add;
    __syncthreads();
  }
  int ex = scn[tx] - v;                    // exclusive prefix
  if (nodeBase + tx < n) rowptr[nodeBase + tx] = segStart + ex;
  hist[tx] = ex;                           // reuse as cursor
  __syncthreads();
  for (int i = segStart + tx; i < segEnd; i += 256) {
    unsigned e = tmp[i];
    int pos = atomicAdd(&hist[e & 255u], 1);
    srcList[segStart + pos] = (int)(e >> 8);
  }
}

// ---------------- Hierarchical exclusive scan (reused for M) ----------------

__global__ void block_reduce(const int* __restrict__ cnt, int* __restrict__ partial, int n) {
  __shared__ int s[256];
  const int t = threadIdx.x;
  const int base = blockIdx.x * 1024;
  int sum = 0;
  for (int i = t; i < 1024; i += 256) {
    int idx = base + i;
    if (idx < n) sum += cnt[idx];
  }
  s[t] = sum;
  __syncthreads();
  for (int off = 128; off > 0; off >>= 1) {
    if (t < off) s[t] += s[t + off];
    __syncthreads();
  }
  if (t == 0) partial[blockIdx.x] = s[0];
}

__global__ void scan_partials(int* __restrict__ partial, int nb, int* __restrict__ total_out) {
  __shared__ int s[256];
  const int t = threadIdx.x;
  int carry = 0;
  for (int base = 0; base < nb; base += 256) {
    int v = (base + t < nb) ? partial[base + t] : 0;
    s[t] = v;
    __syncthreads();
    for (int off = 1; off < 256; off <<= 1) {
      int add = (t >= off) ? s[t - off] : 0;
      __syncthreads();
      s[t] += add;
      __syncthreads();
    }
    if (base + t < nb) partial[base + t] = s[t] - v + carry;
    carry += s[255];
    __syncthreads();
  }
  if (t == 0) *total_out = carry;
}

// In-place-capable: reads all 4 elements before writing.
__global__ void block_scan(int* __restrict__ cnt_cursor, const int* __restrict__ partial,
                           int* __restrict__ outArr, int n) {
  __shared__ int s[256];
  const int t = threadIdx.x;
  const int base = blockIdx.x * 1024;
  int v[4];
  int sum = 0;
#pragma unroll
  for (int j = 0; j < 4; ++j) {
    int idx = base + t * 4 + j;
    v[j] = (idx < n) ? cnt_cursor[idx] : 0;
    sum += v[j];
  }
  s[t] = sum;
  __syncthreads();
  for (int off = 1; off < 256; off <<= 1) {
    int add = (t >= off) ? s[t - off] : 0;
    __syncthreads();
    s[t] += add;
    __syncthreads();
  }
  int excl = s[t] - sum + partial[blockIdx.x];
#pragma unroll
  for (int j = 0; j < 4; ++j) {
    int idx = base + t * 4 + j;
    if (idx < n) {
      outArr[idx] = excl;
      cnt_cursor[idx] = excl;
    }
    excl += v[j];
  }
}

// ------- W transpose+convert to bf16, XOR-swizzled 16B chunks per row -------

struct WConvArgs {
  const float* w[6];
  unsigned short* o[6];
  int K[6], Kp[6];
};

__global__ void wconv(WConvArgs a) {
  const int wi = blockIdx.y;
  const int i = blockIdx.x * 256 + threadIdx.x;
  const int Kp = a.Kp[wi];
  if (i >= H * Kp) return;
  const int nn = i / Kp, k = i - nn * Kp;
  float v = (k < a.K[wi]) ? a.w[wi][(size_t)k * H + nn] : 0.f;
  a.o[wi][(size_t)nn * Kp + (((k >> 3) ^ (nn & 7)) << 3) + (k & 7)] = f2bf(v);
}

// ---------------- Aggregation (gather), bf16 h, swizzled rows ---------------
// One wave per node. Up to 64 src indices preloaded with ONE wave-wide load
// (lane i = index i), distributed via __shfl -> row loads have no address
// dependency and pipeline freely. Two edges per vmem instr (uint2 per lane,
// 32 lanes per row); halves combined via __shfl_down(.,32).

__global__ void gather_h(const unsigned short* __restrict__ h, const int* __restrict__ rowptr,
                         const int* __restrict__ srcList, unsigned short* __restrict__ out, int n) {
  const int node = blockIdx.x;
  const int lane = threadIdx.x;           // 64
  const int half = lane >> 5;
  const int l32 = lane & 31;
  const uint2* h4 = (const uint2*)h;      // row = 32 uint2
  const int c4 = l32 >> 1, p1 = l32 & 1;
  auto rowoff = [&](int r) { return (size_t)r * 32 + (((c4 ^ (r & 7)) << 1) | p1); };

  const int beg = rowptr[node], end = rowptr[node + 1];
  float a0 = 0.f, a1 = 0.f, a2 = 0.f, a3 = 0.f;

  for (int base = beg; base < end; base += 64) {
    const int cnt = min(64, end - base);
    int myidx = (lane < cnt) ? srcList[base + lane] : 0;
    int j = 0;
    for (; j + 7 < cnt; j += 8) {
      int s0 = __shfl(myidx, j + half);
      int s1 = __shfl(myidx, j + 2 + half);
      int s2 = __shfl(myidx, j + 4 + half);
      int s3 = __shfl(myidx, j + 6 + half);
      uint2 v0 = h4[rowoff(s0)];
      uint2 v1 = h4[rowoff(s1)];
      uint2 v2 = h4[rowoff(s2)];
      uint2 v3 = h4[rowoff(s3)];
      a0 += (bf2f((unsigned short)v0.x) + bf2f((unsigned short)v1.x)) +
            (bf2f((unsigned short)v2.x) + bf2f((unsigned short)v3.x));
      a1 += (bf2f((unsigned short)(v0.x >> 16)) + bf2f((unsigned short)(v1.x >> 16))) +
            (bf2f((unsigned short)(v2.x >> 16)) + bf2f((unsigned short)(v3.x >> 16)));
      a2 += (bf2f((unsigned short)v0.y) + bf2f((unsigned short)v1.y)) +
            (bf2f((unsigned short)v2.y) + bf2f((unsigned short)v3.y));
      a3 += (bf2f((unsigned short)(v0.y >> 16)) + bf2f((unsigned short)(v1.y >> 16))) +
            (bf2f((unsigned short)(v2.y >> 16)) + bf2f((unsigned short)(v3.y >> 16)));
    }
    for (; j < cnt; j += 2) {
      const int idx = j + half;
      int s0 = __shfl(myidx, idx & 63);   // all lanes execute the shfl
      if (idx < cnt) {
        uint2 v = h4[rowoff(s0)];
        a0 += bf2f((unsigned short)v.x);
        a1 += bf2f((unsigned short)(v.x >> 16));
        a2 += bf2f((unsigned short)v.y);
        a3 += bf2f((unsigned short)(v.y >> 16));
      }
    }
  }
  // combine halves (lane gets lane+32's accumulators)
  float b0 = __shfl_down(a0, 32), b1 = __shfl_down(a1, 32);
  float b2 = __shfl_down(a2, 32), b3 = __shfl_down(a3, 32);
  if (half == 0) {
    uint2 sv = h4[rowoff(node)];
    a0 += b0 + bf2f((unsigned short)sv.x);
    a1 += b1 + bf2f((unsigned short)(sv.x >> 16));
    a2 += b2 + bf2f((unsigned short)sv.y);
    a3 += b3 + bf2f((unsigned short)(sv.y >> 16));
    uint2 o;
    o.x = ((unsigned)f2bf(a1) << 16) | (unsigned)f2bf(a0);
    o.y = ((unsigned)f2bf(a3) << 16) | (unsigned)f2bf(a2);
    ((uint2*)out)[rowoff(node)] = o;
  }
}

// Layer-1 gather: fp32 x (N x 33) -> bf16 A (N x 64 ushorts, swizzled rows).
// Same preload trick; edge index broadcast via __shfl (uniform lane -> readlane).
__global__ void gather_x(const float* __restrict__ x, const int* __restrict__ rowptr,
                         const int* __restrict__ srcList, unsigned short* __restrict__ out, int n) {
  const int node = blockIdx.x;
  const int lane = threadIdx.x;           // 64
  const int beg = rowptr[node], end = rowptr[node + 1];
  float acc = 0.f;
  if (lane < F_IN) acc = x[(size_t)node * F_IN + lane];

  for (int base = beg; base < end; base += 64) {
    const int cnt = min(64, end - base);
    int myidx = (lane < cnt) ? srcList[base + lane] : 0;
    int j = 0;
    for (; j + 3 < cnt; j += 4) {
      int s0 = __shfl(myidx, j);
      int s1 = __shfl(myidx, j + 1);
      int s2 = __shfl(myidx, j + 2);
      int s3 = __shfl(myidx, j + 3);
      if (lane < F_IN) {
        float v0 = x[(size_t)s0 * F_IN + lane];
        float v1 = x[(size_t)s1 * F_IN + lane];
        float v2 = x[(size_t)s2 * F_IN + lane];
        float v3 = x[(size_t)s3 * F_IN + lane];
        acc += (v0 + v1) + (v2 + v3);
      }
    }
    for (; j < cnt; ++j) {
      int s0 = __shfl(myidx, j);
      if (lane < F_IN) acc += x[(size_t)s0 * F_IN + lane];
    }
  }
  out[(size_t)node * 64 + (((lane >> 3) ^ (node & 7)) << 3) + (lane & 7)] = f2bf(acc);
}

// -------- Fused GIN MLP: C = relu(relu(BN(A@W1)) @ W2 + b2), + pool ---------
// Persistent blocks (grid=256, 1 block/CU): W1,W2 staged to LDS ONCE (async),
// static tile striding. Z stays in LDS. Pool accumulates in LDS; per-block
// partial flushed to a private slab slice, summed by pool_reduce.

template <int K1, bool STORE>
__global__ __launch_bounds__(512, 1) void gin_mlp(
    const unsigned short* __restrict__ Ag,   // n x K1 bf16 (swizzled rows)
    const unsigned short* __restrict__ W1t,  // 128 x K1 bf16 (swizzled)
    const unsigned short* __restrict__ W2t,  // 128 x 128 bf16 (swizzled)
    const float* __restrict__ b1, const float* __restrict__ gam,
    const float* __restrict__ bet, const float* __restrict__ mu,
    const float* __restrict__ var, const float* __restrict__ b2,
    unsigned short* __restrict__ Pout,       // n x 128 bf16 (swizzled) or null
    const int* __restrict__ batch,
    float* __restrict__ slab,                // 256 x 8192 per-block partials
    int n) {
  __shared__ __align__(16) unsigned short W1ls[128 * K1];
  __shared__ __align__(16) unsigned short W2ls[128 * 128];
  __shared__ __align__(16) unsigned short Als[64 * K1];
  __shared__ __align__(16) unsigned short Zls[64 * 128];
  __shared__ __align__(16) float poolLs[GG * H];   // 32 KB
  __shared__ float sc1[128], sh1[128], b2l[128];

  const int tx = threadIdx.x;
  const int wv = tx >> 6;                 // wave 0..7
  const int lane = tx & 63;
  const int q = lane >> 4, m = lane & 15;
  const int rowGroup = (wv >> 1) * 16;    // 0,16,32,48
  const int colHalf = (wv & 1) * 64;
  const int ntiles = (n + 63) >> 6;
  const int step = gridDim.x;

  // Stage W once (async; each wave copies distinct 1024B segments).
  constexpr int W1SEG = 128 * K1 / 512;
  for (int s = wv; s < W1SEG; s += 8)
    ld_lds16(W1t + s * 512 + lane * 8, &W1ls[s * 512]);
  for (int s = wv; s < 32; s += 8)
    ld_lds16(W2t + s * 512 + lane * 8, &W2ls[s * 512]);

  // Zero LDS pool.
  {
    f32x4* pl = (f32x4*)poolLs;
    for (int i = tx; i < GG * H / 4; i += 512) pl[i] = (f32x4)(0.f);
  }
  if (tx < 128) {                          // fold bias1 into BN affine
    float s = gam[tx] * rsqrtf(var[tx] + 1e-5f);
    sc1[tx] = s;
    sh1[tx] = bet[tx] + (b1[tx] - mu[tx]) * s;
  } else if (tx < 256) {
    b2l[tx - 128] = b2[tx - 128];
  }

  int tile = blockIdx.x;
  constexpr int ASEG = 64 * K1 / 512;
  if (tile < ntiles) {
    const unsigned short* src = Ag + (size_t)tile * 64 * K1;
    for (int s = wv; s < ASEG; s += 8)
      ld_lds16(src + s * 512 + lane * 8, &Als[s * 512]);
  }
  __syncthreads();                         // drains W + A(tile)

  while (tile < ntiles) {
    // ---- GEMM1: Z = relu(BN(A @ W1 + b1)) ----
    f32x4 acc[4];
#pragma unroll
    for (int t4 = 0; t4 < 4; ++t4) acc[t4] = (f32x4)(0.f);
    const int am = rowGroup + m;
#pragma unroll
    for (int kc = 0; kc < K1 / 32; ++kc) {
      short8 af = *(const short8*)&Als[am * K1 + (((kc * 4 + q) ^ (am & 7)) << 3)];
#pragma unroll
      for (int t4 = 0; t4 < 4; ++t4) {
        const int bn = colHalf + t4 * 16 + m;
        short8 bf = *(const short8*)&W1ls[bn * K1 + (((kc * 4 + q) ^ (bn & 7)) << 3)];
        acc[t4] = __builtin_amdgcn_mfma_f32_16x16x32_bf16(af, bf, acc[t4], 0, 0, 0);
      }
    }
#pragma unroll
    for (int t4 = 0; t4 < 4; ++t4) {       // epilogue -> Zls (bf16, swizzled)
      const int col = colHalf + t4 * 16 + m;
      const float s = sc1[col], hh = sh1[col];
#pragma unroll
      for (int reg = 0; reg < 4; ++reg) {
        const int r = rowGroup + q * 4 + reg;
        float z = fmaf(acc[t4][reg], s, hh);
        z = z > 0.f ? z : 0.f;
        Zls[r * 128 + (((col >> 3) ^ (r & 7)) << 3) + (col & 7)] = f2bf(z);
      }
    }
    __syncthreads();                       // Zls ready; Als free
    const int nt = tile + step;
    if (nt < ntiles) {                     // prefetch next A, overlaps GEMM2
      const unsigned short* src = Ag + (size_t)nt * 64 * K1;
      for (int s = wv; s < ASEG; s += 8)
        ld_lds16(src + s * 512 + lane * 8, &Als[s * 512]);
    }
    // ---- GEMM2: C = relu(Z @ W2 + b2) ----
#pragma unroll
    for (int t4 = 0; t4 < 4; ++t4) acc[t4] = (f32x4)(0.f);
#pragma unroll
    for (int kc = 0; kc < 4; ++kc) {
      short8 af = *(const short8*)&Zls[am * 128 + (((kc * 4 + q) ^ (am & 7)) << 3)];
#pragma unroll
      for (int t4 = 0; t4 < 4; ++t4) {
        const int bn = colHalf + t4 * 16 + m;
        short8 bf = *(const short8*)&W2ls[bn * 128 + (((kc * 4 + q) ^ (bn & 7)) << 3)];
        acc[t4] = __builtin_amdgcn_mfma_f32_16x16x32_bf16(af, bf, acc[t4], 0, 0, 0);
      }
    }
    const int r0 = tile * 64 + rowGroup + q * 4;
    int gb4[4];
#pragma unroll
    for (int reg = 0; reg < 4; ++reg) gb4[reg] = (r0 + reg < n) ? batch[r0 + reg] : -1;
#pragma unroll
    for (int t4 = 0; t4 < 4; ++t4) {
      const int col = colHalf + t4 * 16 + m;
      float v[4];
#pragma unroll
      for (int reg = 0; reg < 4; ++reg) {
        float z = acc[t4][reg] + b2l[col];
        v[reg] = z > 0.f ? z : 0.f;
      }
      if constexpr (STORE) {
#pragma unroll
        for (int reg = 0; reg < 4; ++reg) {
          const int row = r0 + reg;
          if (row < n)
            Pout[(size_t)row * 128 + (((col >> 3) ^ (row & 7)) << 3) + (col & 7)] = f2bf(v[reg]);
        }
      }
      int gcur = -1; float ps = 0.f;       // batch sorted -> run-length flush
#pragma unroll
      for (int reg = 0; reg < 4; ++reg) {
        if (gb4[reg] < 0) break;
        if (gb4[reg] != gcur) {
          if (gcur >= 0) atomicAdd(&poolLs[gcur * H + col], ps);
          gcur = gb4[reg]; ps = v[reg];
        } else {
          ps += v[reg];
        }
      }
      if (gcur >= 0) atomicAdd(&poolLs[gcur * H + col], ps);
    }
    __syncthreads();                       // drains prefetch; Zls free
    tile = nt;
  }

  // Flush per-block pool partial to private slab slice (no contention).
  __syncthreads();
  {
    const f32x4* pl = (const f32x4*)poolLs;
    f32x4* sl = (f32x4*)(slab + (size_t)blockIdx.x * (GG * H));
    for (int i = tx; i < GG * H / 4; i += 512) sl[i] = pl[i];
  }
}

// Sum 256 per-block slabs -> pools[3][64][128]. o indexes all 3 layers.
__global__ void pool_reduce(const float* __restrict__ slab, float* __restrict__ pools) {
  const int o = blockIdx.x * 256 + threadIdx.x;    // 0 .. 3*8192-1
  const int l = o >> 13;
  const int idx = o & 8191;
  const float* s = slab + (size_t)l * 256 * (GG * H) + idx;
  float acc = 0.f;
#pragma unroll 8
  for (int b = 0; b < 256; ++b) acc += s[(size_t)b * (GG * H)];
  pools[o] = acc;
}

// ---------------- Head MLP: [G,384] -> 50 -> 20 -> 1 -> sigmoid -------------

__global__ void head_kernel(const float* __restrict__ pools,
                            const float* __restrict__ l1w, const float* __restrict__ l1b,
                            const float* __restrict__ l2w, const float* __restrict__ l2b,
                            const float* __restrict__ l3w, const float* __restrict__ l3b,
                            float* __restrict__ out) {
  const int g = blockIdx.x;
  const int t = threadIdx.x;  // 64 threads
  __shared__ float hin[3 * H];
  __shared__ float t1[50];
  __shared__ float t2[20];
  for (int idx = t; idx < 3 * H; idx += 64) {
    int l = idx >> 7, f = idx & 127;
    hin[idx] = pools[(size_t)l * GG * H + (size_t)g * H + f];
  }
  __syncthreads();
  if (t < 50) {
    float s = l1b[t];
    for (int k = 0; k < 3 * H; ++k) s = fmaf(hin[k], l1w[k * 50 + t], s);
    t1[t] = s > 0.f ? s : 0.f;
  }
  __syncthreads();
  if (t < 20) {
    float s = l2b[t];
    for (int k = 0; k < 50; ++k) s = fmaf(t1[k], l2w[k * 20 + t], s);
    t2[t] = s > 0.f ? s : 0.f;
  }
  __syncthreads();
  if (t == 0) {
    float s = l3b[0];
    for (int k = 0; k < 20; ++k) s = fmaf(t2[k], l3w[k], s);
    out[g] = 1.f / (1.f + expf(-s));
  }
}

// ---------------- launch ----------------------------------------------------

extern "C" void kernel_launch(void* const* d_in, const int* in_sizes, int n_in,
                              void* d_out, int out_size, void* d_ws, size_t ws_size,
                              hipStream_t stream) {
  const float* x    = (const float*)d_in[0];
  const int* ei     = (const int*)d_in[1];
  const int* batch  = (const int*)d_in[2];
  const int N = in_sizes[2];
  const int E = in_sizes[1] / 2;
  const int* src = ei;
  const int* dst = ei + E;

  const float* w1[3]; const float* b1[3]; const float* gm[3]; const float* be[3];
  const float* mu[3]; const float* vr[3]; const float* w2[3]; const float* b2[3];
  for (int l = 0; l < 3; ++l) {
    int b = 3 + 8 * l;
    w1[l] = (const float*)d_in[b + 0];
    b1[l] = (const float*)d_in[b + 1];
    gm[l] = (const float*)d_in[b + 2];
    be[l] = (const float*)d_in[b + 3];
    mu[l] = (const float*)d_in[b + 4];
    vr[l] = (const float*)d_in[b + 5];
    w2[l] = (const float*)d_in[b + 6];
    b2[l] = (const float*)d_in[b + 7];
  }
  const float* l1w = (const float*)d_in[27];
  const float* l1b = (const float*)d_in[28];
  const float* l2w = (const float*)d_in[29];
  const float* l2b = (const float*)d_in[30];
  const float* l3w = (const float*)d_in[31];
  const float* l3b = (const float*)d_in[32];

  // workspace carve-up
  char* ws = (char*)d_ws;
  size_t off = 0;
  auto take = [&](size_t bytes) {
    size_t p = off;
    off += (bytes + 255) & ~(size_t)255;
    return p;
  };
  unsigned short* A = (unsigned short*)(ws + take((size_t)N * H * 2));  // agg (bf16, swizzled)
  unsigned short* P = (unsigned short*)(ws + take((size_t)N * H * 2));  // layer out (bf16, swizzled)
  float* pools  = (float*)(ws + take((size_t)3 * GG * H * 4));
  float* slab   = (float*)(ws + take((size_t)3 * 256 * GG * H * 4));    // 24 MB partials
  int* rowptr   = (int*)(ws + take((size_t)(N + 1) * 4));
  int* M        = (int*)(ws + take((size_t)256 * 256 * 4));             // bucket counts/offsets
  int* srcList  = (int*)(ws + take((size_t)E * 4));
  unsigned* tmp = (unsigned*)(ws + take((size_t)E * 4));                // packed (src<<8|dstLocal)
  int* partial  = (int*)(ws + take((size_t)1024 * 4));
  unsigned short* Wt[6];
  for (int i = 0; i < 6; ++i) Wt[i] = (unsigned short*)(ws + take((size_t)H * H * 2));
  (void)ws_size; (void)n_in; (void)out_size;

  const int NBLK = 256;
  const int NB = (N + 255) >> 8;          // buckets of 256 nodes (<= 256)
  const int nscan = NB * NBLK;
  const int nb = (nscan + 1023) / 1024;

  // W transpose+convert+swizzle (all 6 in one launch)
  WConvArgs wa;
  wa.w[0] = w1[0]; wa.K[0] = F_IN; wa.Kp[0] = 64;
  wa.w[1] = w2[0]; wa.K[1] = H;    wa.Kp[1] = H;
  wa.w[2] = w1[1]; wa.K[2] = H;    wa.Kp[2] = H;
  wa.w[3] = w2[1]; wa.K[3] = H;    wa.Kp[3] = H;
  wa.w[4] = w1[2]; wa.K[4] = H;    wa.Kp[4] = H;
  wa.w[5] = w2[2]; wa.K[5] = H;    wa.Kp[5] = H;
  for (int i = 0; i < 6; ++i) wa.o[i] = Wt[i];
  wconv<<<dim3((H * H + 255) / 256, 6), 256, 0, stream>>>(wa);

  // CSR by dst: bucketed counting sort
  csr_p1<<<NBLK, 256, 0, stream>>>(dst, M, E, NB);
  block_reduce<<<nb, 256, 0, stream>>>(M, partial, nscan);
  scan_partials<<<1, 256, 0, stream>>>(partial, nb, rowptr + N);
  block_scan<<<nb, 256, 0, stream>>>(M, partial, M, nscan);   // in-place scan
  csr_p2<<<NBLK, 256, 0, stream>>>(src, dst, M, tmp, E, NB);
  csr_p3<<<NB, 256, 0, stream>>>(tmp, M, rowptr, srcList, N, E, NB, NBLK);

  // ---- layer 1 (K padded 33 -> 64) ----
  gather_x<<<N, 64, 0, stream>>>(x, rowptr, srcList, A, N);
  gin_mlp<64, true><<<256, 512, 0, stream>>>(
      A, Wt[0], Wt[1], b1[0], gm[0], be[0], mu[0], vr[0], b2[0],
      P, batch, slab, N);

  // ---- layer 2 ----
  gather_h<<<N, 64, 0, stream>>>(P, rowptr, srcList, A, N);
  gin_mlp<128, true><<<256, 512, 0, stream>>>(
      A, Wt[2], Wt[3], b1[1], gm[1], be[1], mu[1], vr[1], b2[1],
      P, batch, slab + (size_t)256 * GG * H, N);

  // ---- layer 3 (h3 pooled only) ----
  gather_h<<<N, 64, 0, stream>>>(P, rowptr, srcList, A, N);
  gin_mlp<128, false><<<256, 512, 0, stream>>>(
      A, Wt[4], Wt[5], b1[2], gm[2], be[2], mu[2], vr[2], b2[2],
      nullptr, batch, slab + (size_t)2 * 256 * GG * H, N);

  // ---- pool reduce + head ----
  pool_reduce<<<3 * GG * H / 256, 256, 0, stream>>>(slab, pools);
  head_kernel<<<GG, 64, 0, stream>>>(pools, l1w, l1b, l2w, l2b, l3w, l3b, (float*)d_out);
}

// Round 9
// 340.028 us; speedup vs baseline: 1.4504x; 1.0038x over previous
//
#include <hip/hip_runtime.h>
#include <math.h>

// N=50000 nodes, E=800000 edges, F_IN=33, H=128, G=64 graphs.
static constexpr int F_IN = 33;
static constexpr int H    = 128;
static constexpr int GG   = 64;

typedef __attribute__((ext_vector_type(8))) short short8;
typedef __attribute__((ext_vector_type(4))) float f32x4;

__device__ __forceinline__ unsigned short f2bf(float f) {
  union { float f; unsigned u; } v; v.f = f;
  unsigned r = v.u + 0x7fffu + ((v.u >> 16) & 1u);   // RNE
  return (unsigned short)(r >> 16);
}
__device__ __forceinline__ float bf2f(unsigned short b) {
  union { unsigned u; float f; } v; v.u = ((unsigned)b) << 16;
  return v.f;
}

// Async global->LDS copy, 16B per lane, wave-uniform LDS base (lane-linear).
using gas_u32 = const __attribute__((address_space(1))) unsigned int*;
using las_u32 = __attribute__((address_space(3))) unsigned int*;
__device__ __forceinline__ void ld_lds16(const unsigned short* g, unsigned short* l) {
  __builtin_amdgcn_global_load_lds((gas_u32)(const void*)g, (las_u32)(void*)l, 16, 0, 0);
}

// ---------------- prep: csr hist + W conv + x conv, one launch --------------
// blocks [0,NBLK): per-(bucket,block) LDS hist of dst>>8 -> M
// blocks [NBLK, NBLK+384): W transpose+convert+swizzle (64 blocks per matrix)
// blocks [NBLK+384, ...): x fp32 Nx33 -> bf16 Nx64 swizzled rows (128B)

struct PrepArgs {
  const int* dst; int* M; int E; int NB; int NBLK;
  const float* w[6]; unsigned short* o[6]; int K[6]; int Kp[6];
  const float* x; unsigned short* x64; int N;
};

__global__ void prep(PrepArgs a) {
  const int b = blockIdx.x, tx = threadIdx.x;
  if (b < a.NBLK) {
    __shared__ int hist[256];
    for (int i = tx; i < a.NB; i += 256) hist[i] = 0;
    __syncthreads();
    const int chunk = (a.E + a.NBLK - 1) / a.NBLK;
    const int lo = b * chunk;
    const int hi = min(lo + chunk, a.E);
    for (int i = lo + tx; i < hi; i += 256)
      atomicAdd(&hist[a.dst[i] >> 8], 1);
    __syncthreads();
    for (int bb = tx; bb < a.NB; bb += 256)
      a.M[bb * a.NBLK + b] = hist[bb];
  } else if (b < a.NBLK + 384) {
    const int wb = b - a.NBLK;
    const int wi = wb >> 6;
    const int Kp = a.Kp[wi];
    const int i = (wb & 63) * 256 + tx;
    if (i < H * Kp) {
      const int nn = i / Kp, k = i - nn * Kp;
      float v = (k < a.K[wi]) ? a.w[wi][(size_t)k * H + nn] : 0.f;
      a.o[wi][(size_t)nn * Kp + (((k >> 3) ^ (nn & 7)) << 3) + (k & 7)] = f2bf(v);
    }
  } else {
    const int xb = b - a.NBLK - 384;
    for (int r = 0; r < 4; ++r) {
      const int idx = xb * 1024 + r * 256 + tx;
      const int node = idx >> 6, f = idx & 63;
      if (node < a.N) {
        float v = (f < F_IN) ? a.x[(size_t)node * F_IN + f] : 0.f;
        a.x64[(size_t)node * 64 + (((f >> 3) ^ (node & 7)) << 3) + (f & 7)] = f2bf(v);
      }
    }
  }
}

// ---------------- CSR build: bucketed counting sort (XCD-local writes) ------

__global__ void csr_p2(const int* __restrict__ src, const int* __restrict__ dst,
                       const int* __restrict__ Mscan, unsigned* __restrict__ tmp,
                       int E, int NB) {
  __shared__ int cur[256];
  const int tx = threadIdx.x, blk = blockIdx.x, nblk = gridDim.x;
  for (int b = tx; b < NB; b += 256) cur[b] = Mscan[b * nblk + blk];
  __syncthreads();
  const int chunk = (E + nblk - 1) / nblk;
  const int lo = blk * chunk;
  const int hi = min(lo + chunk, E);
  for (int i = lo + tx; i < hi; i += 256) {
    int d = dst[i];
    int pos = atomicAdd(&cur[d >> 8], 1);
    tmp[pos] = ((unsigned)src[i] << 8) | (unsigned)(d & 255);   // src < 2^24
  }
}

__global__ void csr_p3(const unsigned* __restrict__ tmp, const int* __restrict__ Mscan,
                       int* __restrict__ rowptr, int* __restrict__ srcList,
                       int n, int E, int NB, int NBLK) {
  __shared__ int hist[256];
  __shared__ int scn[256];
  const int b = blockIdx.x, tx = threadIdx.x;
  const int segStart = Mscan[b * NBLK];
  const int segEnd = (b + 1 < NB) ? Mscan[(b + 1) * NBLK] : E;
  const int nodeBase = b << 8;
  hist[tx] = 0;
  __syncthreads();
  for (int i = segStart + tx; i < segEnd; i += 256)
    atomicAdd(&hist[tmp[i] & 255u], 1);
  __syncthreads();
  int v = hist[tx];
  scn[tx] = v;
  __syncthreads();
  for (int off = 1; off < 256; off <<= 1) {
    int add = (tx >= off) ? scn[tx - off] : 0;
    __syncthreads();
    scn[tx] += add;
    __syncthreads();
  }
  int ex = scn[tx] - v;                    // exclusive prefix
  if (nodeBase + tx < n) rowptr[nodeBase + tx] = segStart + ex;
  hist[tx] = ex;                           // reuse as cursor
  __syncthreads();
  for (int i = segStart + tx; i < segEnd; i += 256) {
    unsigned e = tmp[i];
    int pos = atomicAdd(&hist[e & 255u], 1);
    srcList[segStart + pos] = (int)(e >> 8);
  }
}

// ---------------- Hierarchical exclusive scan (for M) -----------------------

__global__ void block_reduce(const int* __restrict__ cnt, int* __restrict__ partial, int n) {
  __shared__ int s[256];
  const int t = threadIdx.x;
  const int base = blockIdx.x * 1024;
  int sum = 0;
  for (int i = t; i < 1024; i += 256) {
    int idx = base + i;
    if (idx < n) sum += cnt[idx];
  }
  s[t] = sum;
  __syncthreads();
  for (int off = 128; off > 0; off >>= 1) {
    if (t < off) s[t] += s[t + off];
    __syncthreads();
  }
  if (t == 0) partial[blockIdx.x] = s[0];
}

__global__ void scan_partials(int* __restrict__ partial, int nb, int* __restrict__ total_out) {
  __shared__ int s[256];
  const int t = threadIdx.x;
  int carry = 0;
  for (int base = 0; base < nb; base += 256) {
    int v = (base + t < nb) ? partial[base + t] : 0;
    s[t] = v;
    __syncthreads();
    for (int off = 1; off < 256; off <<= 1) {
      int add = (t >= off) ? s[t - off] : 0;
      __syncthreads();
      s[t] += add;
      __syncthreads();
    }
    if (base + t < nb) partial[base + t] = s[t] - v + carry;
    carry += s[255];
    __syncthreads();
  }
  if (t == 0) *total_out = carry;
}

// In-place-capable: reads all 4 elements before writing.
__global__ void block_scan(int* __restrict__ cnt_cursor, const int* __restrict__ partial,
                           int* __restrict__ outArr, int n) {
  __shared__ int s[256];
  const int t = threadIdx.x;
  const int base = blockIdx.x * 1024;
  int v[4];
  int sum = 0;
#pragma unroll
  for (int j = 0; j < 4; ++j) {
    int idx = base + t * 4 + j;
    v[j] = (idx < n) ? cnt_cursor[idx] : 0;
    sum += v[j];
  }
  s[t] = sum;
  __syncthreads();
  for (int off = 1; off < 256; off <<= 1) {
    int add = (t >= off) ? s[t - off] : 0;
    __syncthreads();
    s[t] += add;
    __syncthreads();
  }
  int excl = s[t] - sum + partial[blockIdx.x];
#pragma unroll
  for (int j = 0; j < 4; ++j) {
    int idx = base + t * 4 + j;
    if (idx < n) {
      outArr[idx] = excl;
      cnt_cursor[idx] = excl;
    }
    excl += v[j];
  }
}

// ---------------- Aggregation (gather), bf16 h, swizzled rows ---------------
// gather_h: row = 256B = 32 uint2; 2 edges per vmem instr, 16-edge bursts
// (8 independent loads in flight). Halves combined via __shfl_down(.,32).

__global__ void gather_h(const unsigned short* __restrict__ h, const int* __restrict__ rowptr,
                         const int* __restrict__ srcList, unsigned short* __restrict__ out, int n) {
  const int node = blockIdx.x;
  const int lane = threadIdx.x;           // 64
  const int half = lane >> 5;
  const int l32 = lane & 31;
  const uint2* h4 = (const uint2*)h;      // row = 32 uint2
  const int c4 = l32 >> 1, p1 = l32 & 1;
  auto rowoff = [&](int r) { return (size_t)r * 32 + (((c4 ^ (r & 7)) << 1) | p1); };

  const int beg = rowptr[node], end = rowptr[node + 1];
  float a0 = 0.f, a1 = 0.f, a2 = 0.f, a3 = 0.f;

  for (int base = beg; base < end; base += 64) {
    const int cnt = min(64, end - base);
    int myidx = (lane < cnt) ? srcList[base + lane] : 0;
    int j = 0;
    for (; j + 15 < cnt; j += 16) {       // 16 edges, 8 loads in flight
      int s[8];
#pragma unroll
      for (int k = 0; k < 8; ++k) s[k] = __shfl(myidx, j + 2 * k + half);
      uint2 v[8];
#pragma unroll
      for (int k = 0; k < 8; ++k) v[k] = h4[rowoff(s[k])];
#pragma unroll
      for (int k = 0; k < 8; ++k) {
        a0 += bf2f((unsigned short)v[k].x);
        a1 += bf2f((unsigned short)(v[k].x >> 16));
        a2 += bf2f((unsigned short)v[k].y);
        a3 += bf2f((unsigned short)(v[k].y >> 16));
      }
    }
    for (; j < cnt; j += 2) {             // pair tail (+odd via guard)
      const int idx = j + half;
      int s0 = __shfl(myidx, min(idx, cnt - 1));
      if (idx < cnt) {
        uint2 v = h4[rowoff(s0)];
        a0 += bf2f((unsigned short)v.x);
        a1 += bf2f((unsigned short)(v.x >> 16));
        a2 += bf2f((unsigned short)v.y);
        a3 += bf2f((unsigned short)(v.y >> 16));
      }
    }
  }
  float b0 = __shfl_down(a0, 32), b1 = __shfl_down(a1, 32);
  float b2 = __shfl_down(a2, 32), b3 = __shfl_down(a3, 32);
  if (half == 0) {
    uint2 sv = h4[rowoff(node)];
    a0 += b0 + bf2f((unsigned short)sv.x);
    a1 += b1 + bf2f((unsigned short)(sv.x >> 16));
    a2 += b2 + bf2f((unsigned short)sv.y);
    a3 += b3 + bf2f((unsigned short)(sv.y >> 16));
    uint2 o;
    o.x = ((unsigned)f2bf(a1) << 16) | (unsigned)f2bf(a0);
    o.y = ((unsigned)f2bf(a3) << 16) | (unsigned)f2bf(a2);
    ((uint2*)out)[rowoff(node)] = o;
  }
}

// Layer-1 gather on pre-converted x64 (bf16 Nx64 swizzled, 128B rows =
// 16 uint2). 4 edges per vmem instr (16 lanes per row); reduce across
// quarter-groups via shfl_down 32,16; lanes 0-15 add self and store.

__global__ void gather_x2(const unsigned short* __restrict__ x64, const int* __restrict__ rowptr,
                          const int* __restrict__ srcList, unsigned short* __restrict__ out, int n) {
  const int node = blockIdx.x;
  const int lane = threadIdx.x;           // 64
  const int qtr = lane >> 4;
  const int l16 = lane & 15;
  const uint2* h4 = (const uint2*)x64;    // row = 16 uint2
  const int c4 = l16 >> 1, p1 = l16 & 1;
  auto rowoff = [&](int r) { return (size_t)r * 16 + (((c4 ^ (r & 7)) << 1) | p1); };

  const int beg = rowptr[node], end = rowptr[node + 1];
  float a0 = 0.f, a1 = 0.f, a2 = 0.f, a3 = 0.f;

  for (int base = beg; base < end; base += 64) {
    const int cnt = min(64, end - base);
    int myidx = (lane < cnt) ? srcList[base + lane] : 0;
    int j = 0;
    for (; j + 15 < cnt; j += 16) {       // 16 edges, 4 loads in flight
      int s[4];
#pragma unroll
      for (int k = 0; k < 4; ++k) s[k] = __shfl(myidx, j + 4 * k + qtr);
      uint2 v[4];
#pragma unroll
      for (int k = 0; k < 4; ++k) v[k] = h4[rowoff(s[k])];
#pragma unroll
      for (int k = 0; k < 4; ++k) {
        a0 += bf2f((unsigned short)v[k].x);
        a1 += bf2f((unsigned short)(v[k].x >> 16));
        a2 += bf2f((unsigned short)v[k].y);
        a3 += bf2f((unsigned short)(v[k].y >> 16));
      }
    }
    for (; j < cnt; j += 4) {             // quad tail
      const int idx = j + qtr;
      int s0 = __shfl(myidx, min(idx, cnt - 1));
      if (idx < cnt) {
        uint2 v = h4[rowoff(s0)];
        a0 += bf2f((unsigned short)v.x);
        a1 += bf2f((unsigned short)(v.x >> 16));
        a2 += bf2f((unsigned short)v.y);
        a3 += bf2f((unsigned short)(v.y >> 16));
      }
    }
  }
  a0 += __shfl_down(a0, 32); a1 += __shfl_down(a1, 32);
  a2 += __shfl_down(a2, 32); a3 += __shfl_down(a3, 32);
  a0 += __shfl_down(a0, 16); a1 += __shfl_down(a1, 16);
  a2 += __shfl_down(a2, 16); a3 += __shfl_down(a3, 16);
  if (lane < 16) {
    uint2 sv = h4[rowoff(node)];
    a0 += bf2f((unsigned short)sv.x);
    a1 += bf2f((unsigned short)(sv.x >> 16));
    a2 += bf2f((unsigned short)sv.y);
    a3 += bf2f((unsigned short)(sv.y >> 16));
    uint2 o;
    o.x = ((unsigned)f2bf(a1) << 16) | (unsigned)f2bf(a0);
    o.y = ((unsigned)f2bf(a3) << 16) | (unsigned)f2bf(a2);
    ((uint2*)out)[rowoff(node)] = o;
  }
}

// -------- Fused GIN MLP: C = relu(relu(BN(A@W1)) @ W2 + b2), + pool ---------

template <int K1, bool STORE>
__global__ __launch_bounds__(512, 1) void gin_mlp(
    const unsigned short* __restrict__ Ag,   // n x K1 bf16 (swizzled rows)
    const unsigned short* __restrict__ W1t,  // 128 x K1 bf16 (swizzled)
    const unsigned short* __restrict__ W2t,  // 128 x 128 bf16 (swizzled)
    const float* __restrict__ b1, const float* __restrict__ gam,
    const float* __restrict__ bet, const float* __restrict__ mu,
    const float* __restrict__ var, const float* __restrict__ b2,
    unsigned short* __restrict__ Pout,       // n x 128 bf16 (swizzled) or null
    const int* __restrict__ batch,
    float* __restrict__ slab,                // 256 x 8192 per-block partials
    int n) {
  __shared__ __align__(16) unsigned short W1ls[128 * K1];
  __shared__ __align__(16) unsigned short W2ls[128 * 128];
  __shared__ __align__(16) unsigned short Als[64 * K1];
  __shared__ __align__(16) unsigned short Zls[64 * 128];
  __shared__ __align__(16) float poolLs[GG * H];   // 32 KB
  __shared__ float sc1[128], sh1[128], b2l[128];

  const int tx = threadIdx.x;
  const int wv = tx >> 6;                 // wave 0..7
  const int lane = tx & 63;
  const int q = lane >> 4, m = lane & 15;
  const int rowGroup = (wv >> 1) * 16;    // 0,16,32,48
  const int colHalf = (wv & 1) * 64;
  const int ntiles = (n + 63) >> 6;
  const int step = gridDim.x;

  // Stage W once (async; each wave copies distinct 1024B segments).
  constexpr int W1SEG = 128 * K1 / 512;
  for (int s = wv; s < W1SEG; s += 8)
    ld_lds16(W1t + s * 512 + lane * 8, &W1ls[s * 512]);
  for (int s = wv; s < 32; s += 8)
    ld_lds16(W2t + s * 512 + lane * 8, &W2ls[s * 512]);

  // Zero LDS pool.
  {
    f32x4* pl = (f32x4*)poolLs;
    for (int i = tx; i < GG * H / 4; i += 512) pl[i] = (f32x4)(0.f);
  }
  if (tx < 128) {                          // fold bias1 into BN affine
    float s = gam[tx] * rsqrtf(var[tx] + 1e-5f);
    sc1[tx] = s;
    sh1[tx] = bet[tx] + (b1[tx] - mu[tx]) * s;
  } else if (tx < 256) {
    b2l[tx - 128] = b2[tx - 128];
  }

  int tile = blockIdx.x;
  constexpr int ASEG = 64 * K1 / 512;
  if (tile < ntiles) {
    const unsigned short* src = Ag + (size_t)tile * 64 * K1;
    for (int s = wv; s < ASEG; s += 8)
      ld_lds16(src + s * 512 + lane * 8, &Als[s * 512]);
  }
  __syncthreads();                         // drains W + A(tile)

  while (tile < ntiles) {
    // ---- GEMM1: Z = relu(BN(A @ W1 + b1)) ----
    f32x4 acc[4];
#pragma unroll
    for (int t4 = 0; t4 < 4; ++t4) acc[t4] = (f32x4)(0.f);
    const int am = rowGroup + m;
#pragma unroll
    for (int kc = 0; kc < K1 / 32; ++kc) {
      short8 af = *(const short8*)&Als[am * K1 + (((kc * 4 + q) ^ (am & 7)) << 3)];
#pragma unroll
      for (int t4 = 0; t4 < 4; ++t4) {
        const int bn = colHalf + t4 * 16 + m;
        short8 bf = *(const short8*)&W1ls[bn * K1 + (((kc * 4 + q) ^ (bn & 7)) << 3)];
        acc[t4] = __builtin_amdgcn_mfma_f32_16x16x32_bf16(af, bf, acc[t4], 0, 0, 0);
      }
    }
#pragma unroll
    for (int t4 = 0; t4 < 4; ++t4) {       // epilogue -> Zls (bf16, swizzled)
      const int col = colHalf + t4 * 16 + m;
      const float s = sc1[col], hh = sh1[col];
#pragma unroll
      for (int reg = 0; reg < 4; ++reg) {
        const int r = rowGroup + q * 4 + reg;
        float z = fmaf(acc[t4][reg], s, hh);
        z = z > 0.f ? z : 0.f;
        Zls[r * 128 + (((col >> 3) ^ (r & 7)) << 3) + (col & 7)] = f2bf(z);
      }
    }
    __syncthreads();                       // Zls ready; Als free
    const int nt = tile + step;
    if (nt < ntiles) {                     // prefetch next A, overlaps GEMM2
      const unsigned short* src = Ag + (size_t)nt * 64 * K1;
      for (int s = wv; s < ASEG; s += 8)
        ld_lds16(src + s * 512 + lane * 8, &Als[s * 512]);
    }
    // ---- GEMM2: C = relu(Z @ W2 + b2) ----
#pragma unroll
    for (int t4 = 0; t4 < 4; ++t4) acc[t4] = (f32x4)(0.f);
#pragma unroll
    for (int kc = 0; kc < 4; ++kc) {
      short8 af = *(const short8*)&Zls[am * 128 + (((kc * 4 + q) ^ (am & 7)) << 3)];
#pragma unroll
      for (int t4 = 0; t4 < 4; ++t4) {
        const int bn = colHalf + t4 * 16 + m;
        short8 bf = *(const short8*)&W2ls[bn * 128 + (((kc * 4 + q) ^ (bn & 7)) << 3)];
        acc[t4] = __builtin_amdgcn_mfma_f32_16x16x32_bf16(af, bf, acc[t4], 0, 0, 0);
      }
    }
    const int r0 = tile * 64 + rowGroup + q * 4;
    int gb4[4];
#pragma unroll
    for (int reg = 0; reg < 4; ++reg) gb4[reg] = (r0 + reg < n) ? batch[r0 + reg] : -1;
#pragma unroll
    for (int t4 = 0; t4 < 4; ++t4) {
      const int col = colHalf + t4 * 16 + m;
      float v[4];
#pragma unroll
      for (int reg = 0; reg < 4; ++reg) {
        float z = acc[t4][reg] + b2l[col];
        v[reg] = z > 0.f ? z : 0.f;
      }
      if constexpr (STORE) {
#pragma unroll
        for (int reg = 0; reg < 4; ++reg) {
          const int row = r0 + reg;
          if (row < n)
            Pout[(size_t)row * 128 + (((col >> 3) ^ (row & 7)) << 3) + (col & 7)] = f2bf(v[reg]);
        }
      }
      int gcur = -1; float ps = 0.f;       // batch sorted -> run-length flush
#pragma unroll
      for (int reg = 0; reg < 4; ++reg) {
        if (gb4[reg] < 0) break;
        if (gb4[reg] != gcur) {
          if (gcur >= 0) atomicAdd(&poolLs[gcur * H + col], ps);
          gcur = gb4[reg]; ps = v[reg];
        } else {
          ps += v[reg];
        }
      }
      if (gcur >= 0) atomicAdd(&poolLs[gcur * H + col], ps);
    }
    __syncthreads();                       // drains prefetch; Zls free
    tile = nt;
  }

  // Flush per-block pool partial to private slab slice (no contention).
  __syncthreads();
  {
    const f32x4* pl = (const f32x4*)poolLs;
    f32x4* sl = (f32x4*)(slab + (size_t)blockIdx.x * (GG * H));
    for (int i = tx; i < GG * H / 4; i += 512) sl[i] = pl[i];
  }
}

// ------- Head: slab reduce (256 slices x 3 layers) + MLP + sigmoid ----------

__global__ void head2(const float* __restrict__ slab,
                      const float* __restrict__ l1w, const float* __restrict__ l1b,
                      const float* __restrict__ l2w, const float* __restrict__ l2b,
                      const float* __restrict__ l3w, const float* __restrict__ l3b,
                      float* __restrict__ out) {
  const int g = blockIdx.x;
  const int t = threadIdx.x;  // 256 threads
  __shared__ float hin[3 * H];
  __shared__ float t1[50];
  __shared__ float t2[20];
  for (int idx = t; idx < 3 * H; idx += 256) {
    const int l = idx >> 7, f = idx & 127;
    const float* s = slab + (size_t)l * 256 * (GG * H) + (size_t)g * H + f;
    float acc = 0.f;
#pragma unroll 8
    for (int b = 0; b < 256; ++b) acc += s[(size_t)b * (GG * H)];
    hin[idx] = acc;
  }
  __syncthreads();
  if (t < 50) {
    float s = l1b[t];
    for (int k = 0; k < 3 * H; ++k) s = fmaf(hin[k], l1w[k * 50 + t], s);
    t1[t] = s > 0.f ? s : 0.f;
  }
  __syncthreads();
  if (t < 20) {
    float s = l2b[t];
    for (int k = 0; k < 50; ++k) s = fmaf(t1[k], l2w[k * 20 + t], s);
    t2[t] = s > 0.f ? s : 0.f;
  }
  __syncthreads();
  if (t == 0) {
    float s = l3b[0];
    for (int k = 0; k < 20; ++k) s = fmaf(t2[k], l3w[k], s);
    out[g] = 1.f / (1.f + expf(-s));
  }
}

// ---------------- launch ----------------------------------------------------

extern "C" void kernel_launch(void* const* d_in, const int* in_sizes, int n_in,
                              void* d_out, int out_size, void* d_ws, size_t ws_size,
                              hipStream_t stream) {
  const float* x    = (const float*)d_in[0];
  const int* ei     = (const int*)d_in[1];
  const int* batch  = (const int*)d_in[2];
  const int N = in_sizes[2];
  const int E = in_sizes[1] / 2;
  const int* src = ei;
  const int* dst = ei + E;

  const float* w1[3]; const float* b1[3]; const float* gm[3]; const float* be[3];
  const float* mu[3]; const float* vr[3]; const float* w2[3]; const float* b2[3];
  for (int l = 0; l < 3; ++l) {
    int b = 3 + 8 * l;
    w1[l] = (const float*)d_in[b + 0];
    b1[l] = (const float*)d_in[b + 1];
    gm[l] = (const float*)d_in[b + 2];
    be[l] = (const float*)d_in[b + 3];
    mu[l] = (const float*)d_in[b + 4];
    vr[l] = (const float*)d_in[b + 5];
    w2[l] = (const float*)d_in[b + 6];
    b2[l] = (const float*)d_in[b + 7];
  }
  const float* l1w = (const float*)d_in[27];
  const float* l1b = (const float*)d_in[28];
  const float* l2w = (const float*)d_in[29];
  const float* l2b = (const float*)d_in[30];
  const float* l3w = (const float*)d_in[31];
  const float* l3b = (const float*)d_in[32];

  // workspace carve-up
  char* ws = (char*)d_ws;
  size_t off = 0;
  auto take = [&](size_t bytes) {
    size_t p = off;
    off += (bytes + 255) & ~(size_t)255;
    return p;
  };
  unsigned short* A  = (unsigned short*)(ws + take((size_t)N * H * 2));   // agg (bf16, swizzled)
  unsigned short* P  = (unsigned short*)(ws + take((size_t)N * H * 2));   // layer out (bf16, swizzled)
  unsigned short* x64= (unsigned short*)(ws + take((size_t)N * 64 * 2));  // x as bf16 Nx64 swizzled
  float* slab   = (float*)(ws + take((size_t)3 * 256 * GG * H * 4));      // 24 MB partials
  int* rowptr   = (int*)(ws + take((size_t)(N + 1) * 4));
  int* M        = (int*)(ws + take((size_t)256 * 256 * 4));               // bucket counts/offsets
  int* srcList  = (int*)(ws + take((size_t)E * 4));
  unsigned* tmp = (unsigned*)(ws + take((size_t)E * 4));                  // packed (src<<8|dstLocal)
  int* partial  = (int*)(ws + take((size_t)1024 * 4));
  unsigned short* Wt[6];
  for (int i = 0; i < 6; ++i) Wt[i] = (unsigned short*)(ws + take((size_t)H * H * 2));
  (void)ws_size; (void)n_in; (void)out_size;

  const int NBLK = 256;
  const int NB = (N + 255) >> 8;          // buckets of 256 nodes (<= 256)
  const int nscan = NB * NBLK;
  const int nb = (nscan + 1023) / 1024;
  const int XB = ((size_t)N * 64 + 1023) / 1024;

  // prep: csr hist + wconv + xconv, one launch
  PrepArgs pa;
  pa.dst = dst; pa.M = M; pa.E = E; pa.NB = NB; pa.NBLK = NBLK;
  pa.w[0] = w1[0]; pa.K[0] = F_IN; pa.Kp[0] = 64;
  pa.w[1] = w2[0]; pa.K[1] = H;    pa.Kp[1] = H;
  pa.w[2] = w1[1]; pa.K[2] = H;    pa.Kp[2] = H;
  pa.w[3] = w2[1]; pa.K[3] = H;    pa.Kp[3] = H;
  pa.w[4] = w1[2]; pa.K[4] = H;    pa.Kp[4] = H;
  pa.w[5] = w2[2]; pa.K[5] = H;    pa.Kp[5] = H;
  for (int i = 0; i < 6; ++i) pa.o[i] = Wt[i];
  pa.x = x; pa.x64 = x64; pa.N = N;
  prep<<<NBLK + 384 + XB, 256, 0, stream>>>(pa);

  // CSR by dst: scan M, scatter
  block_reduce<<<nb, 256, 0, stream>>>(M, partial, nscan);
  scan_partials<<<1, 256, 0, stream>>>(partial, nb, rowptr + N);
  block_scan<<<nb, 256, 0, stream>>>(M, partial, M, nscan);   // in-place scan
  csr_p2<<<NBLK, 256, 0, stream>>>(src, dst, M, tmp, E, NB);
  csr_p3<<<NB, 256, 0, stream>>>(tmp, M, rowptr, srcList, N, E, NB, NBLK);

  // ---- layer 1 (K padded 33 -> 64) ----
  gather_x2<<<N, 64, 0, stream>>>(x64, rowptr, srcList, A, N);
  gin_mlp<64, true><<<256, 512, 0, stream>>>(
      A, Wt[0], Wt[1], b1[0], gm[0], be[0], mu[0], vr[0], b2[0],
      P, batch, slab, N);

  // ---- layer 2 ----
  gather_h<<<N, 64, 0, stream>>>(P, rowptr, srcList, A, N);
  gin_mlp<128, true><<<256, 512, 0, stream>>>(
      A, Wt[2], Wt[3], b1[1], gm[1], be[1], mu[1], vr[1], b2[1],
      P, batch, slab + (size_t)256 * GG * H, N);

  // ---- layer 3 (h3 pooled only) ----
  gather_h<<<N, 64, 0, stream>>>(P, rowptr, srcList, A, N);
  gin_mlp<128, false><<<256, 512, 0, stream>>>(
      A, Wt[4], Wt[5], b1[2], gm[2], be[2], mu[2], vr[2], b2[2],
      nullptr, batch, slab + (size_t)2 * 256 * GG * H, N);

  // ---- head (slab reduce + MLP + sigmoid) ----
  head2<<<GG, 256, 0, stream>>>(slab, l1w, l1b, l2w, l2b, l3w, l3b, (float*)d_out);
}

// Round 10
// 339.871 us; speedup vs baseline: 1.4511x; 1.0005x over previous
//
#include <hip/hip_runtime.h>
#include <math.h>

// N=50000 nodes, E=800000 edges, F_IN=33, H=128, G=64 graphs.
static constexpr int F_IN = 33;
static constexpr int H    = 128;
static constexpr int GG   = 64;

typedef __attribute__((ext_vector_type(8))) short short8;
typedef __attribute__((ext_vector_type(4))) float f32x4;

__device__ __forceinline__ unsigned short f2bf(float f) {
  union { float f; unsigned u; } v; v.f = f;
  unsigned r = v.u + 0x7fffu + ((v.u >> 16) & 1u);   // RNE
  return (unsigned short)(r >> 16);
}
__device__ __forceinline__ float bf2f(unsigned short b) {
  union { unsigned u; float f; } v; v.u = ((unsigned)b) << 16;
  return v.f;
}

// Async global->LDS copy, 16B per lane, wave-uniform LDS base (lane-linear).
using gas_u32 = const __attribute__((address_space(1))) unsigned int*;
using las_u32 = __attribute__((address_space(3))) unsigned int*;
__device__ __forceinline__ void ld_lds16(const unsigned short* g, unsigned short* l) {
  __builtin_amdgcn_global_load_lds((gas_u32)(const void*)g, (las_u32)(void*)l, 16, 0, 0);
}

// ---------------- prep: csr hist + W conv + x conv, one launch --------------

struct PrepArgs {
  const int* dst; int* M; int E; int NB; int NBLK;
  const float* w[6]; unsigned short* o[6]; int K[6]; int Kp[6];
  const float* x; unsigned short* x64; int N;
};

__global__ void prep(PrepArgs a) {
  const int b = blockIdx.x, tx = threadIdx.x;
  if (b < a.NBLK) {
    __shared__ int hist[256];
    for (int i = tx; i < a.NB; i += 256) hist[i] = 0;
    __syncthreads();
    const int chunk = (a.E + a.NBLK - 1) / a.NBLK;
    const int lo = b * chunk;
    const int hi = min(lo + chunk, a.E);
    for (int i = lo + tx; i < hi; i += 256)
      atomicAdd(&hist[a.dst[i] >> 8], 1);
    __syncthreads();
    for (int bb = tx; bb < a.NB; bb += 256)
      a.M[bb * a.NBLK + b] = hist[bb];
  } else if (b < a.NBLK + 384) {
    const int wb = b - a.NBLK;
    const int wi = wb >> 6;
    const int Kp = a.Kp[wi];
    const int i = (wb & 63) * 256 + tx;
    if (i < H * Kp) {
      const int nn = i / Kp, k = i - nn * Kp;
      float v = (k < a.K[wi]) ? a.w[wi][(size_t)k * H + nn] : 0.f;
      a.o[wi][(size_t)nn * Kp + (((k >> 3) ^ (nn & 7)) << 3) + (k & 7)] = f2bf(v);
    }
  } else {
    const int xb = b - a.NBLK - 384;
    for (int r = 0; r < 4; ++r) {
      const int idx = xb * 1024 + r * 256 + tx;
      const int node = idx >> 6, f = idx & 63;
      if (node < a.N) {
        float v = (f < F_IN) ? a.x[(size_t)node * F_IN + f] : 0.f;
        a.x64[(size_t)node * 64 + (((f >> 3) ^ (node & 7)) << 3) + (f & 7)] = f2bf(v);
      }
    }
  }
}

// ---------------- CSR: per-bucket scan of M + bucket totals -----------------
// M[b*NBLK + blk] (counts) -> within-bucket exclusive prefix (in place);
// bucketTotal[b] = bucket edge count.

__global__ void scanA(int* __restrict__ M, int* __restrict__ bucketTotal, int NBLK) {
  __shared__ int scn[256];
  const int b = blockIdx.x, t = threadIdx.x;
  int v = M[b * NBLK + t];
  scn[t] = v;
  __syncthreads();
  for (int off = 1; off < 256; off <<= 1) {
    int add = (t >= off) ? scn[t - off] : 0;
    __syncthreads();
    scn[t] += add;
    __syncthreads();
  }
  M[b * NBLK + t] = scn[t] - v;
  if (t == 255) bucketTotal[b] = scn[255];
}

// Scatter packed (src<<8 | dst&255) into bucket-partitioned tmp.
// Bucket base offsets re-derived locally from bucketTotal (tiny scan).
__global__ void csr_p2(const int* __restrict__ src, const int* __restrict__ dst,
                       const int* __restrict__ M, const int* __restrict__ bucketTotal,
                       unsigned* __restrict__ tmp, int E, int NB) {
  __shared__ int scn[256];
  __shared__ int cur[256];
  const int tx = threadIdx.x, blk = blockIdx.x, nblk = gridDim.x;
  int v = (tx < NB) ? bucketTotal[tx] : 0;
  scn[tx] = v;
  __syncthreads();
  for (int off = 1; off < 256; off <<= 1) {
    int add = (tx >= off) ? scn[tx - off] : 0;
    __syncthreads();
    scn[tx] += add;
    __syncthreads();
  }
  int e = scn[tx] - v;                    // exclusive bucket offset
  __syncthreads();
  scn[tx] = e;
  __syncthreads();
  for (int b = tx; b < NB; b += 256) cur[b] = M[b * nblk + blk] + scn[b];
  __syncthreads();
  const int chunk = (E + nblk - 1) / nblk;
  const int lo = blk * chunk;
  const int hi = min(lo + chunk, E);
  for (int i = lo + tx; i < hi; i += 256) {
    int d = dst[i];
    int pos = atomicAdd(&cur[d >> 8], 1);
    tmp[pos] = ((unsigned)src[i] << 8) | (unsigned)(d & 255);   // src < 2^24
  }
}

__global__ void csr_p3(const unsigned* __restrict__ tmp, const int* __restrict__ bucketTotal,
                       int* __restrict__ rowptr, int* __restrict__ srcList,
                       int n, int E, int NB) {
  __shared__ int scn[256];
  __shared__ int hist[256];
  __shared__ int s2[256];
  const int b = blockIdx.x, tx = threadIdx.x;
  int v = (tx < NB) ? bucketTotal[tx] : 0;
  scn[tx] = v;
  __syncthreads();
  for (int off = 1; off < 256; off <<= 1) {
    int add = (tx >= off) ? scn[tx - off] : 0;
    __syncthreads();
    scn[tx] += add;
    __syncthreads();
  }
  int e = scn[tx] - v;
  __syncthreads();
  scn[tx] = e;
  __syncthreads();
  const int segStart = scn[b];
  const int segEnd = (b + 1 < NB) ? scn[b + 1] : E;
  if (b == 0 && tx == 0) rowptr[n] = E;
  const int nodeBase = b << 8;
  hist[tx] = 0;
  __syncthreads();
  for (int i = segStart + tx; i < segEnd; i += 256)
    atomicAdd(&hist[tmp[i] & 255u], 1);
  __syncthreads();
  int hv = hist[tx];
  s2[tx] = hv;
  __syncthreads();
  for (int off = 1; off < 256; off <<= 1) {
    int add = (tx >= off) ? s2[tx - off] : 0;
    __syncthreads();
    s2[tx] += add;
    __syncthreads();
  }
  int ex = s2[tx] - hv;                    // exclusive prefix within bucket
  if (nodeBase + tx < n) rowptr[nodeBase + tx] = segStart + ex;
  hist[tx] = ex;                           // reuse as cursor
  __syncthreads();
  for (int i = segStart + tx; i < segEnd; i += 256) {
    unsigned ee = tmp[i];
    int pos = atomicAdd(&hist[ee & 255u], 1);
    srcList[segStart + pos] = (int)(ee >> 8);
  }
}

// ---------------- Aggregation (gather), bf16, swizzled rows, uint4 ----------
// gather_h: row = 256B = 16 uint4; 16 lanes/row -> 4 edges per vmem instr,
// 16-edge burst = 4 instructions. 4 nodes per 256-thr block (wave per node).

__global__ void gather_h(const unsigned short* __restrict__ h, const int* __restrict__ rowptr,
                         const int* __restrict__ srcList, unsigned short* __restrict__ out, int n) {
  const int tx = threadIdx.x;
  const int node = blockIdx.x * 4 + (tx >> 6);
  if (node >= n) return;
  const int lane = tx & 63;
  const int grp = lane >> 4;              // 4 edge-groups
  const int l16 = lane & 15;              // logical 16B chunk
  const uint4* h16 = (const uint4*)h;     // row = 16 uint4
  auto roff = [&](int r) { return (size_t)r * 16 + (l16 ^ (r & 7)); };

  const int beg = rowptr[node], end = rowptr[node + 1];
  float a0=0,a1=0,a2=0,a3=0,a4=0,a5=0,a6=0,a7=0;
  auto addv = [&](uint4 vv) {
    a0 += bf2f((unsigned short)vv.x); a1 += bf2f((unsigned short)(vv.x >> 16));
    a2 += bf2f((unsigned short)vv.y); a3 += bf2f((unsigned short)(vv.y >> 16));
    a4 += bf2f((unsigned short)vv.z); a5 += bf2f((unsigned short)(vv.z >> 16));
    a6 += bf2f((unsigned short)vv.w); a7 += bf2f((unsigned short)(vv.w >> 16));
  };

  for (int base = beg; base < end; base += 64) {
    const int cnt = min(64, end - base);
    int myidx = (lane < cnt) ? srcList[base + lane] : 0;
    int j = 0;
    for (; j + 15 < cnt; j += 16) {       // 16 edges: 4 instrs, 16 rows in flight
      int s[4];
#pragma unroll
      for (int k = 0; k < 4; ++k) s[k] = __shfl(myidx, j + 4 * k + grp);
      uint4 v[4];
#pragma unroll
      for (int k = 0; k < 4; ++k) v[k] = h16[roff(s[k])];
#pragma unroll
      for (int k = 0; k < 4; ++k) addv(v[k]);
    }
    for (; j < cnt; j += 4) {             // quad tail
      const int idx = j + grp;
      int s0 = __shfl(myidx, min(idx, cnt - 1));
      if (idx < cnt) addv(h16[roff(s0)]);
    }
  }
#pragma unroll
  for (int d = 32; d >= 16; d >>= 1) {
    a0 += __shfl_down(a0, d); a1 += __shfl_down(a1, d);
    a2 += __shfl_down(a2, d); a3 += __shfl_down(a3, d);
    a4 += __shfl_down(a4, d); a5 += __shfl_down(a5, d);
    a6 += __shfl_down(a6, d); a7 += __shfl_down(a7, d);
  }
  if (lane < 16) {
    addv(h16[roff(node)]);                // self term
    uint4 o;
    o.x = ((unsigned)f2bf(a1) << 16) | (unsigned)f2bf(a0);
    o.y = ((unsigned)f2bf(a3) << 16) | (unsigned)f2bf(a2);
    o.z = ((unsigned)f2bf(a5) << 16) | (unsigned)f2bf(a4);
    o.w = ((unsigned)f2bf(a7) << 16) | (unsigned)f2bf(a6);
    ((uint4*)out)[(size_t)node * 16 + (l16 ^ (node & 7))] = o;
  }
}

// Layer-1 gather on x64 (bf16 Nx64 swizzled, 128B rows = 8 uint4):
// 8 lanes/row -> 8 edges per vmem instr; 16-edge burst = 2 instructions.

__global__ void gather_x4(const unsigned short* __restrict__ x64, const int* __restrict__ rowptr,
                          const int* __restrict__ srcList, unsigned short* __restrict__ out, int n) {
  const int tx = threadIdx.x;
  const int node = blockIdx.x * 4 + (tx >> 6);
  if (node >= n) return;
  const int lane = tx & 63;
  const int grp = lane >> 3;              // 8 edge-groups
  const int l8 = lane & 7;                // logical 16B chunk
  const uint4* h16 = (const uint4*)x64;   // row = 8 uint4
  auto roff = [&](int r) { return (size_t)r * 8 + (l8 ^ (r & 7)); };

  const int beg = rowptr[node], end = rowptr[node + 1];
  float a0=0,a1=0,a2=0,a3=0,a4=0,a5=0,a6=0,a7=0;
  auto addv = [&](uint4 vv) {
    a0 += bf2f((unsigned short)vv.x); a1 += bf2f((unsigned short)(vv.x >> 16));
    a2 += bf2f((unsigned short)vv.y); a3 += bf2f((unsigned short)(vv.y >> 16));
    a4 += bf2f((unsigned short)vv.z); a5 += bf2f((unsigned short)(vv.z >> 16));
    a6 += bf2f((unsigned short)vv.w); a7 += bf2f((unsigned short)(vv.w >> 16));
  };

  for (int base = beg; base < end; base += 64) {
    const int cnt = min(64, end - base);
    int myidx = (lane < cnt) ? srcList[base + lane] : 0;
    int j = 0;
    for (; j + 15 < cnt; j += 16) {       // 16 edges: 2 instrs
      int s[2];
#pragma unroll
      for (int k = 0; k < 2; ++k) s[k] = __shfl(myidx, j + 8 * k + grp);
      uint4 v[2];
#pragma unroll
      for (int k = 0; k < 2; ++k) v[k] = h16[roff(s[k])];
#pragma unroll
      for (int k = 0; k < 2; ++k) addv(v[k]);
    }
    for (; j < cnt; j += 8) {             // oct tail
      const int idx = j + grp;
      int s0 = __shfl(myidx, min(idx, cnt - 1));
      if (idx < cnt) addv(h16[roff(s0)]);
    }
  }
#pragma unroll
  for (int d = 32; d >= 8; d >>= 1) {
    a0 += __shfl_down(a0, d); a1 += __shfl_down(a1, d);
    a2 += __shfl_down(a2, d); a3 += __shfl_down(a3, d);
    a4 += __shfl_down(a4, d); a5 += __shfl_down(a5, d);
    a6 += __shfl_down(a6, d); a7 += __shfl_down(a7, d);
  }
  if (lane < 8) {
    addv(h16[roff(node)]);                // self term
    uint4 o;
    o.x = ((unsigned)f2bf(a1) << 16) | (unsigned)f2bf(a0);
    o.y = ((unsigned)f2bf(a3) << 16) | (unsigned)f2bf(a2);
    o.z = ((unsigned)f2bf(a5) << 16) | (unsigned)f2bf(a4);
    o.w = ((unsigned)f2bf(a7) << 16) | (unsigned)f2bf(a6);
    ((uint4*)out)[(size_t)node * 8 + (l8 ^ (node & 7))] = o;
  }
}

// -------- Fused GIN MLP: C = relu(relu(BN(A@W1)) @ W2 + b2), + pool ---------

template <int K1, bool STORE>
__global__ __launch_bounds__(512, 1) void gin_mlp(
    const unsigned short* __restrict__ Ag,   // n x K1 bf16 (swizzled rows)
    const unsigned short* __restrict__ W1t,  // 128 x K1 bf16 (swizzled)
    const unsigned short* __restrict__ W2t,  // 128 x 128 bf16 (swizzled)
    const float* __restrict__ b1, const float* __restrict__ gam,
    const float* __restrict__ bet, const float* __restrict__ mu,
    const float* __restrict__ var, const float* __restrict__ b2,
    unsigned short* __restrict__ Pout,       // n x 128 bf16 (swizzled) or null
    const int* __restrict__ batch,
    float* __restrict__ slab,                // 256 x 8192 per-block partials
    int n) {
  __shared__ __align__(16) unsigned short W1ls[128 * K1];
  __shared__ __align__(16) unsigned short W2ls[128 * 128];
  __shared__ __align__(16) unsigned short Als[64 * K1];
  __shared__ __align__(16) unsigned short Zls[64 * 128];
  __shared__ __align__(16) float poolLs[GG * H];   // 32 KB
  __shared__ float sc1[128], sh1[128], b2l[128];

  const int tx = threadIdx.x;
  const int wv = tx >> 6;                 // wave 0..7
  const int lane = tx & 63;
  const int q = lane >> 4, m = lane & 15;
  const int rowGroup = (wv >> 1) * 16;    // 0,16,32,48
  const int colHalf = (wv & 1) * 64;
  const int ntiles = (n + 63) >> 6;
  const int step = gridDim.x;

  // Stage W once (async; each wave copies distinct 1024B segments).
  constexpr int W1SEG = 128 * K1 / 512;
  for (int s = wv; s < W1SEG; s += 8)
    ld_lds16(W1t + s * 512 + lane * 8, &W1ls[s * 512]);
  for (int s = wv; s < 32; s += 8)
    ld_lds16(W2t + s * 512 + lane * 8, &W2ls[s * 512]);

  // Zero LDS pool.
  {
    f32x4* pl = (f32x4*)poolLs;
    for (int i = tx; i < GG * H / 4; i += 512) pl[i] = (f32x4)(0.f);
  }
  if (tx < 128) {                          // fold bias1 into BN affine
    float s = gam[tx] * rsqrtf(var[tx] + 1e-5f);
    sc1[tx] = s;
    sh1[tx] = bet[tx] + (b1[tx] - mu[tx]) * s;
  } else if (tx < 256) {
    b2l[tx - 128] = b2[tx - 128];
  }

  int tile = blockIdx.x;
  constexpr int ASEG = 64 * K1 / 512;
  if (tile < ntiles) {
    const unsigned short* src = Ag + (size_t)tile * 64 * K1;
    for (int s = wv; s < ASEG; s += 8)
      ld_lds16(src + s * 512 + lane * 8, &Als[s * 512]);
  }
  __syncthreads();                         // drains W + A(tile)

  while (tile < ntiles) {
    // ---- GEMM1: Z = relu(BN(A @ W1 + b1)) ----
    f32x4 acc[4];
#pragma unroll
    for (int t4 = 0; t4 < 4; ++t4) acc[t4] = (f32x4)(0.f);
    const int am = rowGroup + m;
#pragma unroll
    for (int kc = 0; kc < K1 / 32; ++kc) {
      short8 af = *(const short8*)&Als[am * K1 + (((kc * 4 + q) ^ (am & 7)) << 3)];
#pragma unroll
      for (int t4 = 0; t4 < 4; ++t4) {
        const int bn = colHalf + t4 * 16 + m;
        short8 bf = *(const short8*)&W1ls[bn * K1 + (((kc * 4 + q) ^ (bn & 7)) << 3)];
        acc[t4] = __builtin_amdgcn_mfma_f32_16x16x32_bf16(af, bf, acc[t4], 0, 0, 0);
      }
    }
#pragma unroll
    for (int t4 = 0; t4 < 4; ++t4) {       // epilogue -> Zls (bf16, swizzled)
      const int col = colHalf + t4 * 16 + m;
      const float s = sc1[col], hh = sh1[col];
#pragma unroll
      for (int reg = 0; reg < 4; ++reg) {
        const int r = rowGroup + q * 4 + reg;
        float z = fmaf(acc[t4][reg], s, hh);
        z = z > 0.f ? z : 0.f;
        Zls[r * 128 + (((col >> 3) ^ (r & 7)) << 3) + (col & 7)] = f2bf(z);
      }
    }
    __syncthreads();                       // Zls ready; Als free
    const int nt = tile + step;
    if (nt < ntiles) {                     // prefetch next A, overlaps GEMM2
      const unsigned short* src = Ag + (size_t)nt * 64 * K1;
      for (int s = wv; s < ASEG; s += 8)
        ld_lds16(src + s * 512 + lane * 8, &Als[s * 512]);
    }
    // ---- GEMM2: C = relu(Z @ W2 + b2) ----
#pragma unroll
    for (int t4 = 0; t4 < 4; ++t4) acc[t4] = (f32x4)(0.f);
#pragma unroll
    for (int kc = 0; kc < 4; ++kc) {
      short8 af = *(const short8*)&Zls[am * 128 + (((kc * 4 + q) ^ (am & 7)) << 3)];
#pragma unroll
      for (int t4 = 0; t4 < 4; ++t4) {
        const int bn = colHalf + t4 * 16 + m;
        short8 bf = *(const short8*)&W2ls[bn * 128 + (((kc * 4 + q) ^ (bn & 7)) << 3)];
        acc[t4] = __builtin_amdgcn_mfma_f32_16x16x32_bf16(af, bf, acc[t4], 0, 0, 0);
      }
    }
    const int r0 = tile * 64 + rowGroup + q * 4;
    int gb4[4];
#pragma unroll
    for (int reg = 0; reg < 4; ++reg) gb4[reg] = (r0 + reg < n) ? batch[r0 + reg] : -1;
#pragma unroll
    for (int t4 = 0; t4 < 4; ++t4) {
      const int col = colHalf + t4 * 16 + m;
      float v[4];
#pragma unroll
      for (int reg = 0; reg < 4; ++reg) {
        float z = acc[t4][reg] + b2l[col];
        v[reg] = z > 0.f ? z : 0.f;
      }
      if constexpr (STORE) {
#pragma unroll
        for (int reg = 0; reg < 4; ++reg) {
          const int row = r0 + reg;
          if (row < n)
            Pout[(size_t)row * 128 + (((col >> 3) ^ (row & 7)) << 3) + (col & 7)] = f2bf(v[reg]);
        }
      }
      int gcur = -1; float ps = 0.f;       // batch sorted -> run-length flush
#pragma unroll
      for (int reg = 0; reg < 4; ++reg) {
        if (gb4[reg] < 0) break;
        if (gb4[reg] != gcur) {
          if (gcur >= 0) atomicAdd(&poolLs[gcur * H + col], ps);
          gcur = gb4[reg]; ps = v[reg];
        } else {
          ps += v[reg];
        }
      }
      if (gcur >= 0) atomicAdd(&poolLs[gcur * H + col], ps);
    }
    __syncthreads();                       // drains prefetch; Zls free
    tile = nt;
  }

  // Flush per-block pool partial to private slab slice (no contention).
  __syncthreads();
  {
    const f32x4* pl = (const f32x4*)poolLs;
    f32x4* sl = (f32x4*)(slab + (size_t)blockIdx.x * (GG * H));
    for (int i = tx; i < GG * H / 4; i += 512) sl[i] = pl[i];
  }
}

// ------- Head: slab reduce (256 slices x 3 layers) + MLP + sigmoid ----------

__global__ void head2(const float* __restrict__ slab,
                      const float* __restrict__ l1w, const float* __restrict__ l1b,
                      const float* __restrict__ l2w, const float* __restrict__ l2b,
                      const float* __restrict__ l3w, const float* __restrict__ l3b,
                      float* __restrict__ out) {
  const int g = blockIdx.x;
  const int t = threadIdx.x;  // 256 threads
  __shared__ float hin[3 * H];
  __shared__ float t1[50];
  __shared__ float t2[20];
  for (int idx = t; idx < 3 * H; idx += 256) {
    const int l = idx >> 7, f = idx & 127;
    const float* s = slab + (size_t)l * 256 * (GG * H) + (size_t)g * H + f;
    float acc = 0.f;
#pragma unroll 8
    for (int b = 0; b < 256; ++b) acc += s[(size_t)b * (GG * H)];
    hin[idx] = acc;
  }
  __syncthreads();
  if (t < 50) {
    float s = l1b[t];
    for (int k = 0; k < 3 * H; ++k) s = fmaf(hin[k], l1w[k * 50 + t], s);
    t1[t] = s > 0.f ? s : 0.f;
  }
  __syncthreads();
  if (t < 20) {
    float s = l2b[t];
    for (int k = 0; k < 50; ++k) s = fmaf(t1[k], l2w[k * 20 + t], s);
    t2[t] = s > 0.f ? s : 0.f;
  }
  __syncthreads();
  if (t == 0) {
    float s = l3b[0];
    for (int k = 0; k < 20; ++k) s = fmaf(t2[k], l3w[k], s);
    out[g] = 1.f / (1.f + expf(-s));
  }
}

// ---------------- launch ----------------------------------------------------

extern "C" void kernel_launch(void* const* d_in, const int* in_sizes, int n_in,
                              void* d_out, int out_size, void* d_ws, size_t ws_size,
                              hipStream_t stream) {
  const float* x    = (const float*)d_in[0];
  const int* ei     = (const int*)d_in[1];
  const int* batch  = (const int*)d_in[2];
  const int N = in_sizes[2];
  const int E = in_sizes[1] / 2;
  const int* src = ei;
  const int* dst = ei + E;

  const float* w1[3]; const float* b1[3]; const float* gm[3]; const float* be[3];
  const float* mu[3]; const float* vr[3]; const float* w2[3]; const float* b2[3];
  for (int l = 0; l < 3; ++l) {
    int b = 3 + 8 * l;
    w1[l] = (const float*)d_in[b + 0];
    b1[l] = (const float*)d_in[b + 1];
    gm[l] = (const float*)d_in[b + 2];
    be[l] = (const float*)d_in[b + 3];
    mu[l] = (const float*)d_in[b + 4];
    vr[l] = (const float*)d_in[b + 5];
    w2[l] = (const float*)d_in[b + 6];
    b2[l] = (const float*)d_in[b + 7];
  }
  const float* l1w = (const float*)d_in[27];
  const float* l1b = (const float*)d_in[28];
  const float* l2w = (const float*)d_in[29];
  const float* l2b = (const float*)d_in[30];
  const float* l3w = (const float*)d_in[31];
  const float* l3b = (const float*)d_in[32];

  // workspace carve-up
  char* ws = (char*)d_ws;
  size_t off = 0;
  auto take = [&](size_t bytes) {
    size_t p = off;
    off += (bytes + 255) & ~(size_t)255;
    return p;
  };
  unsigned short* A  = (unsigned short*)(ws + take((size_t)N * H * 2));   // agg (bf16, swizzled)
  unsigned short* P  = (unsigned short*)(ws + take((size_t)N * H * 2));   // layer out (bf16, swizzled)
  unsigned short* x64= (unsigned short*)(ws + take((size_t)N * 64 * 2));  // x as bf16 Nx64 swizzled
  float* slab   = (float*)(ws + take((size_t)3 * 256 * GG * H * 4));      // 24 MB partials
  int* rowptr   = (int*)(ws + take((size_t)(N + 1) * 4));
  int* M        = (int*)(ws + take((size_t)256 * 256 * 4));               // bucket counts/offsets
  int* srcList  = (int*)(ws + take((size_t)E * 4));
  unsigned* tmp = (unsigned*)(ws + take((size_t)E * 4));                  // packed (src<<8|dstLocal)
  int* bucketTotal = (int*)(ws + take((size_t)256 * 4));
  unsigned short* Wt[6];
  for (int i = 0; i < 6; ++i) Wt[i] = (unsigned short*)(ws + take((size_t)H * H * 2));
  (void)ws_size; (void)n_in; (void)out_size;

  const int NBLK = 256;
  const int NB = (N + 255) >> 8;          // buckets of 256 nodes (<= 256)
  const int XB = ((size_t)N * 64 + 1023) / 1024;
  const int GB = (N + 3) / 4;             // gather blocks (4 nodes each)

  // prep: csr hist + wconv + xconv, one launch
  PrepArgs pa;
  pa.dst = dst; pa.M = M; pa.E = E; pa.NB = NB; pa.NBLK = NBLK;
  pa.w[0] = w1[0]; pa.K[0] = F_IN; pa.Kp[0] = 64;
  pa.w[1] = w2[0]; pa.K[1] = H;    pa.Kp[1] = H;
  pa.w[2] = w1[1]; pa.K[2] = H;    pa.Kp[2] = H;
  pa.w[3] = w2[1]; pa.K[3] = H;    pa.Kp[3] = H;
  pa.w[4] = w1[2]; pa.K[4] = H;    pa.Kp[4] = H;
  pa.w[5] = w2[2]; pa.K[5] = H;    pa.Kp[5] = H;
  for (int i = 0; i < 6; ++i) pa.o[i] = Wt[i];
  pa.x = x; pa.x64 = x64; pa.N = N;
  prep<<<NBLK + 384 + XB, 256, 0, stream>>>(pa);

  // CSR: per-bucket scan, scatter to tmp, final sort into srcList + rowptr
  scanA<<<NB, 256, 0, stream>>>(M, bucketTotal, NBLK);
  csr_p2<<<NBLK, 256, 0, stream>>>(src, dst, M, bucketTotal, tmp, E, NB);
  csr_p3<<<NB, 256, 0, stream>>>(tmp, bucketTotal, rowptr, srcList, N, E, NB);

  // ---- layer 1 (K padded 33 -> 64) ----
  gather_x4<<<GB, 256, 0, stream>>>(x64, rowptr, srcList, A, N);
  gin_mlp<64, true><<<256, 512, 0, stream>>>(
      A, Wt[0], Wt[1], b1[0], gm[0], be[0], mu[0], vr[0], b2[0],
      P, batch, slab, N);

  // ---- layer 2 ----
  gather_h<<<GB, 256, 0, stream>>>(P, rowptr, srcList, A, N);
  gin_mlp<128, true><<<256, 512, 0, stream>>>(
      A, Wt[2], Wt[3], b1[1], gm[1], be[1], mu[1], vr[1], b2[1],
      P, batch, slab + (size_t)256 * GG * H, N);

  // ---- layer 3 (h3 pooled only) ----
  gather_h<<<GB, 256, 0, stream>>>(P, rowptr, srcList, A, N);
  gin_mlp<128, false><<<256, 512, 0, stream>>>(
      A, Wt[4], Wt[5], b1[2], gm[2], be[2], mu[2], vr[2], b2[2],
      nullptr, batch, slab + (size_t)2 * 256 * GG * H, N);

  // ---- head (slab reduce + MLP + sigmoid) ----
  head2<<<GG, 256, 0, stream>>>(slab, l1w, l1b, l2w, l2b, l3w, l3b, (float*)d_out);
}